// Round 9
// baseline (404.320 us; speedup 1.0000x reference)
//
#include <hip/hip_runtime.h>
#include <hip/hip_bf16.h>
#include <math.h>

#define DM   1024   // d_model
#define DI   2048   // d_inner
#define DTR  64     // dt_rank
#define DST  16     // d_state
#define NB   2      // batch
#define LL   1024   // seq len
#define MR   (NB*LL)  // 2048 rows
#define XLD  128    // xdb padded leading dim

typedef __bf16 bf16x8 __attribute__((ext_vector_type(8)));
typedef float  f32x4  __attribute__((ext_vector_type(4)));
typedef unsigned short u16x8 __attribute__((ext_vector_type(8)));

__device__ __forceinline__ float siluf(float x) { return x / (1.f + __expf(-x)); }
__device__ __forceinline__ float softplusf(float x) {
    return fmaxf(x, 0.f) + log1pf(__expf(-fabsf(x)));
}
__device__ __forceinline__ unsigned short f2bf(float f) {
    __hip_bfloat16 h = __float2bfloat16(f);
    return *reinterpret_cast<unsigned short*>(&h);
}
__device__ __forceinline__ float bf2f(__hip_bfloat16 h) { return __bfloat162float(h); }
__device__ __forceinline__ float bfu2f(unsigned short u) {
    __hip_bfloat16 h = *reinterpret_cast<__hip_bfloat16*>(&u);
    return __bfloat162float(h);
}

__device__ __forceinline__ void gl2lds16(const __hip_bfloat16* g, __hip_bfloat16* l)
{
    __builtin_amdgcn_global_load_lds(
        (const __attribute__((address_space(1))) unsigned int*)g,
        (__attribute__((address_space(3))) unsigned int*)l, 16, 0, 0);
}

// ---------------- mega-prep: weight cvts + transpose + layernorm ----------------
__global__ __launch_bounds__(256) void prep_k(
    const float* __restrict__ s0, const float* __restrict__ s1,
    const float* __restrict__ s2, const float* __restrict__ s3,
    const float* __restrict__ s4, __hip_bfloat16* __restrict__ warena,
    const float* __restrict__ fx, const float* __restrict__ bx,
    __hip_bfloat16* __restrict__ wpb2,
    const float* __restrict__ fo, const float* __restrict__ bo,
    __hip_bfloat16* __restrict__ wot,
    const float* __restrict__ x, const float* __restrict__ lnw,
    const float* __restrict__ lnb, __hip_bfloat16* __restrict__ nb)
{
    __shared__ float pshm[64 * 65];
    const int b = blockIdx.x;
    const int tid = threadIdx.x;

    if (b < 2624) {
        long base = (long)b * 4096;
        const float* src; long off;
        if      (base <  4194304L) { src = s0; off = base; }
        else if (base <  8388608L) { src = s1; off = base -  4194304L; }
        else if (base < 10485760L) { src = s2; off = base -  8388608L; }
        else if (base < 10616832L) { src = s3; off = base - 10485760L; }
        else                       { src = s4; off = base - 10616832L; }
        #pragma unroll
        for (int j = 0; j < 4; ++j) {
            long e = (long)j * 1024 + tid * 4;
            float4 v = *(const float4*)(src + off + e);
            ushort4 o;
            o.x = f2bf(v.x); o.y = f2bf(v.y); o.z = f2bf(v.z); o.w = f2bf(v.w);
            *(ushort4*)((unsigned short*)warena + base + e) = o;
        }
    } else if (b < 2752) {
        int t = b - 2624;
        int z = t >> 6;
        const float* in = z ? bx : fx;
        int idx = ((t & 63) * 256 + tid) * 4;   // over 128*DI
        int row = idx >> 11;
        ushort4 o = make_ushort4(0, 0, 0, 0);
        if (row < 96) {
            float4 v = *(const float4*)(in + idx);
            o.x = f2bf(v.x); o.y = f2bf(v.y); o.z = f2bf(v.z); o.w = f2bf(v.w);
        }
        *(ushort4*)((unsigned short*)wpb2 + (size_t)z * 128 * DI + idx) = o;
    } else if (b < 3776) {
        int t = b - 2752;
        int z = t >> 9; t &= 511;
        const float* src = z ? bo : fo;
        int c0 = (t & 31) * 64;    // col in src (DI dim)
        int r0 = (t >> 5) * 64;    // row in src (DM dim)
        int tc = tid & 63;
        int tr = tid >> 6;
        #pragma unroll
        for (int ii = 0; ii < 16; ++ii) {
            int rl = tr + ii * 4;
            pshm[tc * 65 + rl] = src[(size_t)(r0 + rl) * DI + c0 + tc];
        }
        __syncthreads();
        __hip_bfloat16* dst = wot + (size_t)z * DI * DM;
        #pragma unroll
        for (int ii = 0; ii < 16; ++ii) {
            int cl = tr + ii * 4;
            dst[(size_t)(c0 + cl) * DM + r0 + tc] = __float2bfloat16(pshm[cl * 65 + tc]);
        }
    } else {
        int row = b - 3776;
        const float* xr = x + (size_t)row * DM;
        float4 v = *(const float4*)(xr + tid * 4);
        float s = v.x + v.y + v.z + v.w;
        float q = v.x*v.x + v.y*v.y + v.z*v.z + v.w*v.w;
        #pragma unroll
        for (int off = 32; off > 0; off >>= 1) {
            s += __shfl_xor(s, off, 64);
            q += __shfl_xor(q, off, 64);
        }
        int wv = tid >> 6;
        if ((tid & 63) == 0) { pshm[wv] = s; pshm[8 + wv] = q; }
        __syncthreads();
        s = pshm[0] + pshm[1] + pshm[2] + pshm[3];
        q = pshm[8] + pshm[9] + pshm[10] + pshm[11];
        float mu  = s * (1.f / DM);
        float var = q * (1.f / DM) - mu * mu;
        float rstd = rsqrtf(var + 1e-5f);
        float4 wv4 = *(const float4*)(lnw + tid * 4);
        float4 bv4 = *(const float4*)(lnb + tid * 4);
        ushort4 o;
        o.x = f2bf((v.x - mu) * rstd * wv4.x + bv4.x);
        o.y = f2bf((v.y - mu) * rstd * wv4.y + bv4.y);
        o.z = f2bf((v.z - mu) * rstd * wv4.z + bv4.z);
        o.w = f2bf((v.w - mu) * rstd * wv4.w + bv4.w);
        *(ushort4*)((unsigned short*)nb + (size_t)row * DM + tid * 4) = o;
    }
}

// ---------------- in-proj: 256x256, BK=64, 4-phase/tile ----------------
__global__ __launch_bounds__(512) void inproj256_k(
    const __hip_bfloat16* __restrict__ A,
    const __hip_bfloat16* __restrict__ Bmat,
    __hip_bfloat16* __restrict__ C)
{
    __shared__ __hip_bfloat16 smem[65536];   // 128 KiB
    const int tid = threadIdx.x;
    int id = blockIdx.x;
    int s  = (id & 7) * 32 + (id >> 3);
    const int z  = s >> 7;
    const int r  = s & 127;
    const int bm = (r & 7) * 256;
    const int bn = (r >> 3) * 256;
    const __hip_bfloat16* Az = A;
    const __hip_bfloat16* Bz = Bmat + (size_t)z * 2 * DI * DM;
    __hip_bfloat16* Cz = C + (size_t)z * MR * 2 * DI;

    const int wv   = tid >> 6;
    const int lane = tid & 63;
    const int wm   = wv >> 2;      // 0..1
    const int wn   = wv & 3;       // 0..3
    const int fr   = lane & 15;
    const int quad = lane >> 4;

    const int srow = tid >> 2;                       // 0..127
    const int scol = 8 * ((tid & 3) ^ ((tid >> 3) & 3));
    const int kph  = (quad ^ ((fr >> 1) & 3)) * 8;

    __hip_bfloat16* const Asl = smem;          // [2][2][256][32]
    __hip_bfloat16* const Bsl = smem + 32768;

    f32x4 acc[8][4] = {};
    bf16x8 aF[4], bB[4];

#define STG_A(TAU, KK) { \
    const int ub_ = (((TAU) & 1) * 2 + (KK)) * 8192; \
    const int gc_ = (TAU) * 64 + (KK) * 32 + scol; \
    gl2lds16(Az + (size_t)(bm + srow) * DM + gc_,       Asl + ub_ + tid * 8); \
    gl2lds16(Az + (size_t)(bm + 128 + srow) * DM + gc_, Asl + ub_ + 4096 + tid * 8); }
#define STG_B(TAU, KK) { \
    const int ub_ = (((TAU) & 1) * 2 + (KK)) * 8192; \
    const int gc_ = (TAU) * 64 + (KK) * 32 + scol; \
    gl2lds16(Bz + (size_t)(bn + srow) * DM + gc_,       Bsl + ub_ + tid * 8); \
    gl2lds16(Bz + (size_t)(bn + 128 + srow) * DM + gc_, Bsl + ub_ + 4096 + tid * 8); }

#define RD_A(BUF, KK, MH) { \
    const __hip_bfloat16* p_ = Asl + ((BUF) * 2 + (KK)) * 8192 + kph; \
    _Pragma("unroll") for (int i = 0; i < 4; ++i) \
        aF[i] = *(const bf16x8*)(p_ + (wm * 128 + (MH) * 64 + i * 16 + fr) * 32); }
#define RD_B(BUF, KK) { \
    const __hip_bfloat16* p_ = Bsl + ((BUF) * 2 + (KK)) * 8192 + kph; \
    _Pragma("unroll") for (int j = 0; j < 4; ++j) \
        bB[j] = *(const bf16x8*)(p_ + (wn * 64 + j * 16 + fr) * 32); }

#define PHASE(BUF, KK, MH, STGC, T1, T2, VMC) { \
    if ((MH) == 0) { RD_B(BUF, KK); } \
    RD_A(BUF, KK, MH); \
    if ((STGC) == 1) { STG_A((T1), 1); } \
    if ((STGC) == 2) { STG_B((T1), 1); } \
    if ((STGC) == 3) { STG_A((T2), 0); } \
    if ((STGC) == 4) { STG_B((T2), 0); } \
    asm volatile("s_barrier" ::: "memory"); \
    asm volatile("s_waitcnt lgkmcnt(0)" ::: "memory"); \
    __builtin_amdgcn_sched_barrier(0); \
    __builtin_amdgcn_s_setprio(1); \
    _Pragma("unroll") for (int i = 0; i < 4; ++i) \
        _Pragma("unroll") for (int j = 0; j < 4; ++j) \
            acc[(MH) * 4 + i][j] = __builtin_amdgcn_mfma_f32_16x16x32_bf16( \
                aF[i], bB[j], acc[(MH) * 4 + i][j], 0, 0, 0); \
    __builtin_amdgcn_s_setprio(0); \
    if ((VMC) == 8) { asm volatile("s_waitcnt vmcnt(8)" ::: "memory"); } \
    if ((VMC) == 4) { asm volatile("s_waitcnt vmcnt(4)" ::: "memory"); } \
    if ((VMC) == 1) { asm volatile("s_waitcnt vmcnt(0)" ::: "memory"); } \
    asm volatile("s_barrier" ::: "memory"); }

    STG_A(0, 0); STG_B(0, 0); STG_A(0, 1); STG_B(0, 1); STG_A(1, 0); STG_B(1, 0);
    asm volatile("s_waitcnt vmcnt(8)" ::: "memory");
    asm volatile("s_barrier" ::: "memory");

    #pragma unroll 1
    for (int t = 0; t < 14; ++t) {
        const int buf = t & 1;
        const int t1 = t + 1, t2 = t + 2;
        PHASE(buf, 0, 0, 1, t1, t2, 0);
        PHASE(buf, 0, 1, 2, t1, t2, 8);
        PHASE(buf, 1, 0, 3, t1, t2, 0);
        PHASE(buf, 1, 1, 4, t1, t2, 8);
    }
    PHASE(0, 0, 0, 1, 15, 0, 0);
    PHASE(0, 0, 1, 2, 15, 0, 8);
    PHASE(0, 1, 0, 0, 0, 0, 0);
    PHASE(0, 1, 1, 0, 0, 0, 4);
    PHASE(1, 0, 0, 0, 0, 0, 0);
    PHASE(1, 0, 1, 0, 0, 0, 1);
    PHASE(1, 1, 0, 0, 0, 0, 0);
    PHASE(1, 1, 1, 0, 0, 0, 0);

#undef PHASE
#undef RD_A
#undef RD_B
#undef STG_A
#undef STG_B

    // epilogue: 4 passes of 64 rows via LDS restage -> 64 B/thread stores
    float* eps = (float*)smem;
    const int orow = tid >> 3;          // 0..63
    const int ocol = (tid & 7) * 32;    // 0..224
    #pragma unroll
    for (int p = 0; p < 4; ++p) {
        __syncthreads();
        if (wm == (p >> 1)) {
            int ib = (p & 1) * 4;
            #pragma unroll
            for (int i2 = 0; i2 < 4; ++i2)
                #pragma unroll
                for (int j = 0; j < 4; ++j)
                    #pragma unroll
                    for (int rr = 0; rr < 4; ++rr)
                        eps[(i2 * 16 + quad * 4 + rr) * 260 + wn * 64 + j * 16 + fr]
                            = acc[ib + i2][j][rr];
        }
        __syncthreads();
        unsigned short os[32] __attribute__((aligned(16)));
        #pragma unroll
        for (int c = 0; c < 32; ++c) os[c] = f2bf(eps[orow * 260 + ocol + c]);
        unsigned short* dst = (unsigned short*)Cz +
            (size_t)(bm + p * 64 + orow) * (2 * DI) + bn + ocol;
        *(uint4*)(dst +  0) = *(const uint4*)(os +  0);
        *(uint4*)(dst +  8) = *(const uint4*)(os +  8);
        *(uint4*)(dst + 16) = *(const uint4*)(os + 16);
        *(uint4*)(dst + 24) = *(const uint4*)(os + 24);
    }
}

// ---------------- bf16 MFMA GEMM with global_load_lds staging ----------------
// EPI: 1 = bf16 store, 3 = softplus(v+bias_z[n]) bf16 store.
template<int EPI>
__global__ __launch_bounds__(256) void gemm_gl(
    const __hip_bfloat16* __restrict__ A, int lda, size_t aofs,
    const __hip_bfloat16* __restrict__ B, int ldb, size_t bofs,
    void* __restrict__ Cp, int ldc, size_t cofs, int K,
    const float* __restrict__ bias0, const float* __restrict__ bias1)
{
    __shared__ __hip_bfloat16 smem[2 * 128 * 64];
    __hip_bfloat16* As = smem;
    __hip_bfloat16* Bs = smem + 128 * 64;
    const int tid  = threadIdx.x;
    const int z    = blockIdx.z;
    const int bm   = blockIdx.y * 128;
    const int bn   = blockIdx.x * 128;
    const __hip_bfloat16* Az = A + (size_t)z * aofs;
    const __hip_bfloat16* Bz = B + (size_t)z * bofs;
    const int wv   = tid >> 6;
    const int lane = tid & 63;
    const int wr   = (wv >> 1) * 64;
    const int wc   = (wv & 1) * 64;
    const int srow = wv * 32 + (lane >> 3);
    const int cg   = ((lane & 7) ^ (lane >> 3)) * 8;
    const int fr   = lane & 15;
    const int quad = lane >> 4;
    const int pc0  = (quad ^ (fr & 7)) * 8;
    const int pc1  = ((4 + quad) ^ (fr & 7)) * 8;

    f32x4 acc[4][4] = {};

    for (int k0 = 0; k0 < K; k0 += 64) {
        __syncthreads();
        #pragma unroll
        for (int i = 0; i < 4; ++i) {
            int r = srow + i * 8;
            gl2lds16(Az + (size_t)(bm + r) * lda + k0 + cg, As + wv * 2048 + i * 512);
            gl2lds16(Bz + (size_t)(bn + r) * ldb + k0 + cg, Bs + wv * 2048 + i * 512);
        }
        __syncthreads();
        #pragma unroll
        for (int kk = 0; kk < 2; ++kk) {
            const int pc = kk ? pc1 : pc0;
            bf16x8 af[4], bf_[4];
            #pragma unroll
            for (int i = 0; i < 4; ++i) {
                af[i]  = *(const bf16x8*)(As + (wr + i * 16 + fr) * 64 + pc);
                bf_[i] = *(const bf16x8*)(Bs + (wc + i * 16 + fr) * 64 + pc);
            }
            #pragma unroll
            for (int i = 0; i < 4; ++i)
                #pragma unroll
                for (int j = 0; j < 4; ++j)
                    acc[i][j] = __builtin_amdgcn_mfma_f32_16x16x32_bf16(
                        af[i], bf_[j], acc[i][j], 0, 0, 0);
        }
    }

    const float* bias = (EPI == 3) ? (z ? bias1 : bias0) : nullptr;
    float* eps = (float*)smem;
    const int half = wv >> 1;
    const int lrow = tid >> 3;
    const int cseg = (tid & 7) * 16;
    const int gr_  = bm + (lrow >> 4) * 64 + (lrow & 15);
    #pragma unroll
    for (int i = 0; i < 4; ++i) {
        __syncthreads();
        #pragma unroll
        for (int j = 0; j < 4; ++j)
            #pragma unroll
            for (int r = 0; r < 4; ++r)
                eps[(half * 16 + quad * 4 + r) * 132 + wc + j * 16 + fr] = acc[i][j][r];
        __syncthreads();
        float vals[16];
        *(float4*)(vals +  0) = *(const float4*)(eps + lrow * 132 + cseg +  0);
        *(float4*)(vals +  4) = *(const float4*)(eps + lrow * 132 + cseg +  4);
        *(float4*)(vals +  8) = *(const float4*)(eps + lrow * 132 + cseg +  8);
        *(float4*)(vals + 12) = *(const float4*)(eps + lrow * 132 + cseg + 12);
        int gr = gr_ + i * 16;
        int gc = bn + cseg;
        unsigned short os[16];
        #pragma unroll
        for (int c = 0; c < 16; ++c) {
            float t = vals[c];
            if (EPI == 3) t = softplusf(t + bias[gc + c]);
            os[c] = f2bf(t);
        }
        unsigned short* dst = (unsigned short*)Cp + (size_t)z * cofs +
                              (size_t)gr * ldc + gc;
        *(ushort4*)(dst +  0) = *(ushort4*)(os +  0);
        *(ushort4*)(dst +  4) = *(ushort4*)(os +  4);
        *(ushort4*)(dst +  8) = *(ushort4*)(os +  8);
        *(ushort4*)(dst + 12) = *(ushort4*)(os + 12);
    }
}

// ---------------- merged conv+silu (blocks 0..1023) + Wcat gemm (1024..1279) ----------------
__global__ __launch_bounds__(256) void conv_wcat_k(
    const __hip_bfloat16* __restrict__ xz2,
    const float* __restrict__ fW, const float* __restrict__ fb,
    const float* __restrict__ bW, const float* __restrict__ bb_,
    __hip_bfloat16* __restrict__ xsb2,
    const __hip_bfloat16* __restrict__ pwb,
    const __hip_bfloat16* __restrict__ wot,
    __hip_bfloat16* __restrict__ wcat)
{
    __shared__ __hip_bfloat16 smem[2 * 128 * 64];
    const int b   = blockIdx.x;
    const int tid = threadIdx.x;

    if (b < 1024) {
        // ---- conv branch ----
        const int dirv  = b >> 9;
        const int chunk = b & 511;
        const int bb    = chunk >> 8;
        const int t0    = (chunk & 255) * 4;
        const int d     = tid * 8;

        const float* w    = (dirv ? bW : fW) + d * 4;
        const float* bias = (dirv ? bb_ : fb) + d;
        const unsigned short* xz =
            (const unsigned short*)(xz2 + (size_t)dirv * MR * 2 * DI) + d;

        u16x8 rows[7];
        #pragma unroll
        for (int rr = 0; rr < 7; ++rr) {
            int t = dirv ? (t0 + rr) : (t0 - 3 + rr);
            bool ok = dirv ? (t < LL) : (t >= 0);
            u16x8 v = {};
            if (ok) v = *(const u16x8*)(xz + (size_t)(bb * LL + t) * (2 * DI));
            rows[rr] = v;
        }
        float wq[8][4];
        #pragma unroll
        for (int c = 0; c < 8; ++c) {
            float4 t = *(const float4*)(w + c * 4);
            if (dirv) { wq[c][0]=t.w; wq[c][1]=t.z; wq[c][2]=t.y; wq[c][3]=t.x; }
            else      { wq[c][0]=t.x; wq[c][1]=t.y; wq[c][2]=t.z; wq[c][3]=t.w; }
        }
        float4 b0 = *(const float4*)(bias);
        float4 b1 = *(const float4*)(bias + 4);
        float bs[8] = {b0.x, b0.y, b0.z, b0.w, b1.x, b1.y, b1.z, b1.w};

        unsigned short* outp = (unsigned short*)xsb2 + (size_t)dirv * MR * DI +
                               (size_t)(bb * LL + t0) * DI + d;
        #pragma unroll
        for (int o = 0; o < 4; ++o) {
            unsigned short os[8] __attribute__((aligned(16)));
            #pragma unroll
            for (int c = 0; c < 8; ++c) {
                float a = bs[c];
                #pragma unroll
                for (int k = 0; k < 4; ++k)
                    a = fmaf(wq[c][k], bfu2f(rows[o + k][c]), a);
                os[c] = f2bf(siluf(a));
            }
            *(uint4*)(outp + (size_t)o * DI) = *(const uint4*)os;
        }
        return;
    }

    // ---- wcat branch: gemm body, lda=2*DM, ldb=DM, ldc=2*DI, K=DM ----
    const int t_   = b - 1024;
    const int bn   = (t_ & 15) * 128;         // over DI cols
    const int bm   = ((t_ >> 4) & 7) * 128;   // over DM rows
    const int z    = t_ >> 7;                 // dir
    const __hip_bfloat16* Az = pwb + (size_t)z * DM;
    const __hip_bfloat16* Bz = wot + (size_t)z * DI * DM;
    __hip_bfloat16* As = smem;
    __hip_bfloat16* Bs = smem + 128 * 64;
    const int wv   = tid >> 6;
    const int lane = tid & 63;
    const int wr   = (wv >> 1) * 64;
    const int wc   = (wv & 1) * 64;
    const int srow = wv * 32 + (lane >> 3);
    const int cg   = ((lane & 7) ^ (lane >> 3)) * 8;
    const int fr   = lane & 15;
    const int quad = lane >> 4;
    const int pc0  = (quad ^ (fr & 7)) * 8;
    const int pc1  = ((4 + quad) ^ (fr & 7)) * 8;

    f32x4 acc[4][4] = {};

    for (int k0 = 0; k0 < DM; k0 += 64) {
        __syncthreads();
        #pragma unroll
        for (int i = 0; i < 4; ++i) {
            int r = srow + i * 8;
            gl2lds16(Az + (size_t)(bm + r) * (2 * DM) + k0 + cg, As + wv * 2048 + i * 512);
            gl2lds16(Bz + (size_t)(bn + r) * DM + k0 + cg,       Bs + wv * 2048 + i * 512);
        }
        __syncthreads();
        #pragma unroll
        for (int kk = 0; kk < 2; ++kk) {
            const int pc = kk ? pc1 : pc0;
            bf16x8 af[4], bf_[4];
            #pragma unroll
            for (int i = 0; i < 4; ++i) {
                af[i]  = *(const bf16x8*)(As + (wr + i * 16 + fr) * 64 + pc);
                bf_[i] = *(const bf16x8*)(Bs + (wc + i * 16 + fr) * 64 + pc);
            }
            #pragma unroll
            for (int i = 0; i < 4; ++i)
                #pragma unroll
                for (int j = 0; j < 4; ++j)
                    acc[i][j] = __builtin_amdgcn_mfma_f32_16x16x32_bf16(
                        af[i], bf_[j], acc[i][j], 0, 0, 0);
        }
    }

    float* eps = (float*)smem;
    const int half = wv >> 1;
    const int lrow = tid >> 3;
    const int cseg = (tid & 7) * 16;
    const int gr_  = bm + (lrow >> 4) * 64 + (lrow & 15);
    #pragma unroll
    for (int i = 0; i < 4; ++i) {
        __syncthreads();
        #pragma unroll
        for (int j = 0; j < 4; ++j)
            #pragma unroll
            for (int r = 0; r < 4; ++r)
                eps[(half * 16 + quad * 4 + r) * 132 + wc + j * 16 + fr] = acc[i][j][r];
        __syncthreads();
        float vals[16];
        *(float4*)(vals +  0) = *(const float4*)(eps + lrow * 132 + cseg +  0);
        *(float4*)(vals +  4) = *(const float4*)(eps + lrow * 132 + cseg +  4);
        *(float4*)(vals +  8) = *(const float4*)(eps + lrow * 132 + cseg +  8);
        *(float4*)(vals + 12) = *(const float4*)(eps + lrow * 132 + cseg + 12);
        int gr = gr_ + i * 16;
        int gc = bn + cseg;
        unsigned short os[16];
        #pragma unroll
        for (int c = 0; c < 16; ++c) os[c] = f2bf(vals[c]);
        unsigned short* dst = (unsigned short*)wcat + (size_t)z * DI +
                              (size_t)gr * (2 * DI) + gc;
        *(ushort4*)(dst +  0) = *(ushort4*)(os +  0);
        *(ushort4*)(dst +  4) = *(ushort4*)(os +  4);
        *(ushort4*)(dst +  8) = *(ushort4*)(os +  8);
        *(ushort4*)(dst + 12) = *(ushort4*)(os + 12);
    }
}

// ---------------- x-proj direct: xdb[z] = xsb2[z] @ wpb2[z]^T (full K, no partials) ----------------
// Tiles 32x128, full K=DI per block; grid (MR/32=64, 2) = 128 blocks.
// 4 waves (2M x 2N): wave = 16 rows x 64 cols, acc[4] f32x4. Same stage/read
// swizzle pair as gemm_gl. Replaces split-K part+reduce (134 MB partial
// round-trip -> 2.6 MB direct stores) and removes one dispatch.
__global__ __launch_bounds__(256) void xproj64_k(
    const __hip_bfloat16* __restrict__ A,   // xsb2 [2][MR][DI]
    const __hip_bfloat16* __restrict__ B,   // wpb2 [2][128][DI]
    float* __restrict__ xdb,                // [2][MR][XLD]
    __hip_bfloat16* __restrict__ xdbt)      // [2][MR][64]
{
    __shared__ __hip_bfloat16 smem[(32 + 128) * 64];   // 20 KB
    __hip_bfloat16* As = smem;            // [32][64]
    __hip_bfloat16* Bs = smem + 32 * 64;  // [128][64]
    const int tid = threadIdx.x;
    const int z   = blockIdx.y;
    const int bm  = blockIdx.x * 32;
    const __hip_bfloat16* Az = A + (size_t)z * MR * DI;
    const __hip_bfloat16* Bz = B + (size_t)z * 128 * DI;
    const int wv   = tid >> 6;
    const int lane = tid & 63;
    const int wm   = wv >> 1;        // 0..1 (16-row half)
    const int wn   = wv & 1;         // 0..1 (64-col half)
    const int fr   = lane & 15;
    const int quad = lane >> 4;
    const int srow = tid >> 3;       // 0..31
    const int cg   = ((tid & 7) ^ (srow & 7)) * 8;
    const int pc0  = (quad ^ (fr & 7)) * 8;
    const int pc1  = ((4 + quad) ^ (fr & 7)) * 8;

    f32x4 acc[4] = {};

    for (int k0 = 0; k0 < DI; k0 += 64) {
        __syncthreads();
        gl2lds16(Az + (size_t)(bm + srow) * DI + k0 + cg, As + tid * 8);
        #pragma unroll
        for (int i = 0; i < 4; ++i)
            gl2lds16(Bz + (size_t)(i * 32 + srow) * DI + k0 + cg,
                     Bs + i * 2048 + tid * 8);
        __syncthreads();
        #pragma unroll
        for (int kk = 0; kk < 2; ++kk) {
            const int pc = kk ? pc1 : pc0;
            bf16x8 af = *(const bf16x8*)(As + (wm * 16 + fr) * 64 + pc);
            #pragma unroll
            for (int j = 0; j < 4; ++j) {
                bf16x8 bf_ = *(const bf16x8*)(Bs + (wn * 64 + j * 16 + fr) * 64 + pc);
                acc[j] = __builtin_amdgcn_mfma_f32_16x16x32_bf16(af, bf_, acc[j], 0, 0, 0);
            }
        }
    }

    float* xdbz = xdb + (size_t)z * MR * XLD;
    unsigned short* xdtz = (unsigned short*)xdbt + (size_t)z * MR * 64;
    #pragma unroll
    for (int j = 0; j < 4; ++j) {
        const int col = wn * 64 + j * 16 + fr;
        #pragma unroll
        for (int r = 0; r < 4; ++r) {
            const int row = bm + wm * 16 + quad * 4 + r;
            const float v = acc[j][r];
            xdbz[(size_t)row * XLD + col] = v;
            if (wn == 0)   // cols 0..63 = dt-rank block
                xdtz[(size_t)row * 64 + col] = f2bf(v);
        }
    }
}

// ---------------- fused out-proj: out = x + proj_b + ycat @ wcat^T ----------------
__global__ __launch_bounds__(256) void outproj_k(
    const __hip_bfloat16* __restrict__ A,   // ycat [MR][4096]
    const __hip_bfloat16* __restrict__ Bm,  // wcat [DM][4096]
    const float* __restrict__ x, const float* __restrict__ proj_b,
    float* __restrict__ out)
{
    __shared__ __hip_bfloat16 smem[2 * 64 * 64];
    __hip_bfloat16* As = smem;
    __hip_bfloat16* Bs = smem + 64 * 64;
    const int tid  = threadIdx.x;
    const int bn   = blockIdx.x * 64;
    const int bm   = blockIdx.y * 64;
    const int wv   = tid >> 6;
    const int lane = tid & 63;
    const int wr   = (wv >> 1) * 32;
    const int wc   = (wv & 1) * 32;
    const int srow = wv * 16 + (lane >> 3);
    const int cg   = ((lane & 7) ^ (lane >> 3)) * 8;
    const int fr   = lane & 15;
    const int quad = lane >> 4;
    const int pc0  = (quad ^ (fr & 7)) * 8;
    const int pc1  = ((4 + quad) ^ (fr & 7)) * 8;
    const int K    = 2 * DI;

    f32x4 acc[2][2] = {};

    for (int k0 = 0; k0 < K; k0 += 64) {
        __syncthreads();
        #pragma unroll
        for (int j = 0; j < 2; ++j) {
            int r = srow + j * 8;
            gl2lds16(A  + (size_t)(bm + r) * K + k0 + cg, As + wv * 1024 + j * 512);
            gl2lds16(Bm + (size_t)(bn + r) * K + k0 + cg, Bs + wv * 1024 + j * 512);
        }
        __syncthreads();
        #pragma unroll
        for (int kk = 0; kk < 2; ++kk) {
            const int pc = kk ? pc1 : pc0;
            bf16x8 af[2], bf_[2];
            #pragma unroll
            for (int i = 0; i < 2; ++i) {
                af[i]  = *(const bf16x8*)(As + (wr + i * 16 + fr) * 64 + pc);
                bf_[i] = *(const bf16x8*)(Bs + (wc + i * 16 + fr) * 64 + pc);
            }
            #pragma unroll
            for (int i = 0; i < 2; ++i)
                #pragma unroll
                for (int j = 0; j < 2; ++j)
                    acc[i][j] = __builtin_amdgcn_mfma_f32_16x16x32_bf16(
                        af[i], bf_[j], acc[i][j], 0, 0, 0);
        }
    }

    const float pb0 = proj_b[bn + wc + fr];
    const float pb1 = proj_b[bn + wc + 16 + fr];
    #pragma unroll
    for (int i = 0; i < 2; ++i)
        #pragma unroll
        for (int j = 0; j < 2; ++j) {
            const int gc = bn + wc + j * 16 + fr;
            const float pb = j ? pb1 : pb0;
            #pragma unroll
            for (int r = 0; r < 4; ++r) {
                size_t off = (size_t)(bm + wr + i * 16 + quad * 4 + r) * DM + gc;
                out[off] = x[off] + pb + acc[i][j][r];
            }
        }
}

// ---------------- conv fallback (wotInHbuf==0 path) ----------------
__global__ __launch_bounds__(256) void conv_silu_k(
    const __hip_bfloat16* __restrict__ xz2,
    const float* __restrict__ fW, const float* __restrict__ fb,
    const float* __restrict__ bW, const float* __restrict__ bb_,
    __hip_bfloat16* __restrict__ xsb2)
{
    const int dirv  = blockIdx.y;
    const int chunk = blockIdx.x;
    const int bb    = chunk >> 8;
    const int t0    = (chunk & 255) * 4;
    const int d     = threadIdx.x * 8;

    const float* w    = (dirv ? bW : fW) + d * 4;
    const float* bias = (dirv ? bb_ : fb) + d;
    const unsigned short* xz =
        (const unsigned short*)(xz2 + (size_t)dirv * MR * 2 * DI) + d;

    u16x8 rows[7];
    #pragma unroll
    for (int rr = 0; rr < 7; ++rr) {
        int t = dirv ? (t0 + rr) : (t0 - 3 + rr);
        bool ok = dirv ? (t < LL) : (t >= 0);
        u16x8 v = {};
        if (ok) v = *(const u16x8*)(xz + (size_t)(bb * LL + t) * (2 * DI));
        rows[rr] = v;
    }
    float wq[8][4];
    #pragma unroll
    for (int c = 0; c < 8; ++c) {
        float4 t = *(const float4*)(w + c * 4);
        if (dirv) { wq[c][0]=t.w; wq[c][1]=t.z; wq[c][2]=t.y; wq[c][3]=t.x; }
        else      { wq[c][0]=t.x; wq[c][1]=t.y; wq[c][2]=t.z; wq[c][3]=t.w; }
    }
    float4 b0 = *(const float4*)(bias);
    float4 b1 = *(const float4*)(bias + 4);
    float bs[8] = {b0.x, b0.y, b0.z, b0.w, b1.x, b1.y, b1.z, b1.w};

    unsigned short* outp = (unsigned short*)xsb2 + (size_t)dirv * MR * DI +
                           (size_t)(bb * LL + t0) * DI + d;
    #pragma unroll
    for (int o = 0; o < 4; ++o) {
        unsigned short os[8] __attribute__((aligned(16)));
        #pragma unroll
        for (int c = 0; c < 8; ++c) {
            float a = bs[c];
            #pragma unroll
            for (int k = 0; k < 4; ++k)
                a = fmaf(wq[c][k], bfu2f(rows[o + k][c]), a);
            os[c] = f2bf(siluf(a));
        }
        *(uint4*)(outp + (size_t)o * DI) = *(const uint4*)os;
    }
}

// ---------------- Chunked selective scan, both dirs (3-dispatch, proven) ----------------
__global__ __launch_bounds__(256) void scan1_k(
    const __hip_bfloat16* __restrict__ dtf2, const __hip_bfloat16* __restrict__ xsb2,
    const float* __restrict__ xdb2,
    const float* __restrict__ fA, const float* __restrict__ bA,
    float* __restrict__ hend, float* __restrict__ aprod, int G, int Cn)
{
    int d  = blockIdx.x * 256 + threadIdx.x;
    int bb = blockIdx.y;
    int zz = blockIdx.z;
    int dirv = (zz >= G) ? 1 : 0;
    int g = zz - (dirv ? G : 0);
    const float* A_log = dirv ? bA : fA;
    const __hip_bfloat16* dtf = dtf2 + (size_t)dirv * MR * DI;
    const __hip_bfloat16* xs = xsb2 + (size_t)dirv * MR * DI;
    const float* xdb = xdb2 + (size_t)dirv * MR * XLD;
    size_t hoff = (size_t)dirv * G * (NB * DI * DST);

    float Ad[DST], h[DST], ap[DST];
    bool pw = true;
    #pragma unroll
    for (int s = 0; s < DST; ++s) {
        Ad[s] = -__expf(A_log[d * DST + s]);
        pw = pw && (fabsf(Ad[s] + (float)(s + 1)) < 1e-3f * (s + 1));
        h[s] = 0.f; ap[s] = 1.f;
    }
    int i0 = g * Cn;
    for (int i = 0; i < Cn; ++i) {
        int ii = i0 + i;
        int t = dirv ? (LL - 1 - ii) : ii;
        size_t m = (size_t)bb * LL + t;
        float dtv = bf2f(dtf[m * DI + d]);
        float xv  = bf2f(xs[m * DI + d]);
        const float* bc = xdb + m * XLD;
        float dtx = dtv * xv;
        float dAv[DST];
        if (pw) {
            float r = __expf(-dtv);
            float a = r;
            #pragma unroll
            for (int s = 0; s < DST; ++s) { dAv[s] = a; a *= r; }
        } else {
            #pragma unroll
            for (int s = 0; s < DST; ++s) dAv[s] = __expf(dtv * Ad[s]);
        }
        #pragma unroll
        for (int s = 0; s < DST; ++s) {
            h[s] = fmaf(h[s], dAv[s], dtx * bc[64 + s]);
            ap[s] *= dAv[s];
        }
    }
    size_t base = hoff + ((size_t)(g * NB + bb) * DI + d) * DST;
    #pragma unroll
    for (int s = 0; s < DST; s += 4) {
        *(float4*)(hend  + base + s) = make_float4(h[s], h[s+1], h[s+2], h[s+3]);
        *(float4*)(aprod + base + s) = make_float4(ap[s], ap[s+1], ap[s+2], ap[s+3]);
    }
}

__global__ __launch_bounds__(256) void scan2_k(
    float* __restrict__ hend, const float* __restrict__ aprod, int G)
{
    int dirv = blockIdx.y;
    int idx = blockIdx.x * 256 + threadIdx.x;
    const int slab = NB * DI * DST;
    size_t hoff = (size_t)dirv * G * slab;
    float carry = 0.f;
    for (int g = 0; g < G; ++g) {
        size_t off = hoff + (size_t)g * slab + idx;
        float a = aprod[off];
        float e = hend[off];
        hend[off] = carry;
        carry = fmaf(a, carry, e);
    }
}

__global__ __launch_bounds__(256) void scan3_k(
    const __hip_bfloat16* __restrict__ dtf2, const __hip_bfloat16* __restrict__ xsb2,
    const float* __restrict__ xdb2, const __hip_bfloat16* __restrict__ xz2,
    const float* __restrict__ fA, const float* __restrict__ bA,
    const float* __restrict__ fD, const float* __restrict__ bD,
    const float* __restrict__ hin, __hip_bfloat16* __restrict__ ycat, int G, int Cn)
{
    int d  = blockIdx.x * 256 + threadIdx.x;
    int bb = blockIdx.y;
    int zz = blockIdx.z;
    int dirv = (zz >= G) ? 1 : 0;
    int g = zz - (dirv ? G : 0);
    const float* A_log = dirv ? bA : fA;
    const float* Dskip = dirv ? bD : fD;
    const __hip_bfloat16* dtf = dtf2 + (size_t)dirv * MR * DI;
    const __hip_bfloat16* xs = xsb2 + (size_t)dirv * MR * DI;
    const float* xdb = xdb2 + (size_t)dirv * MR * XLD;
    const __hip_bfloat16* xz = xz2 + (size_t)dirv * MR * 2 * DI;
    size_t hoff = (size_t)dirv * G * (NB * DI * DST);

    float Ad[DST], h[DST];
    bool pw = true;
    size_t base = hoff + ((size_t)(g * NB + bb) * DI + d) * DST;
    #pragma unroll
    for (int s = 0; s < DST; ++s) {
        Ad[s] = -__expf(A_log[d * DST + s]);
        pw = pw && (fabsf(Ad[s] + (float)(s + 1)) < 1e-3f * (s + 1));
        h[s] = hin[base + s];
    }
    float Dsk = Dskip[d];
    int i0 = g * Cn;
    for (int i = 0; i < Cn; ++i) {
        int ii = i0 + i;
        int t = dirv ? (LL - 1 - ii) : ii;
        size_t m = (size_t)bb * LL + t;
        float dtv = bf2f(dtf[m * DI + d]);
        float xv  = bf2f(xs[m * DI + d]);
        const float* bc = xdb + m * XLD;
        float dtx = dtv * xv;
        float dAv[DST];
        if (pw) {
            float r = __expf(-dtv);
            float a = r;
            #pragma unroll
            for (int s = 0; s < DST; ++s) { dAv[s] = a; a *= r; }
        } else {
            #pragma unroll
            for (int s = 0; s < DST; ++s) dAv[s] = __expf(dtv * Ad[s]);
        }
        float yv = 0.f;
        #pragma unroll
        for (int s = 0; s < DST; ++s) {
            h[s] = fmaf(h[s], dAv[s], dtx * bc[64 + s]);
            yv = fmaf(h[s], bc[80 + s], yv);
        }
        float zv = bf2f(xz[m * (2 * DI) + DI + d]);
        ycat[m * (2 * DI) + (size_t)dirv * DI + d] =
            __float2bfloat16((yv + xv * Dsk) * siluf(zv));
    }
}

// fallback monolithic scan (both dirs) if ws too small for chunk bufs
__global__ __launch_bounds__(256) void scan_mono_k(
    const __hip_bfloat16* __restrict__ dtf2, const __hip_bfloat16* __restrict__ xsb2,
    const float* __restrict__ xdb2, const __hip_bfloat16* __restrict__ xz2,
    const float* __restrict__ fA, const float* __restrict__ bA,
    const float* __restrict__ fD, const float* __restrict__ bD,
    __hip_bfloat16* __restrict__ ycat)
{
    int d  = blockIdx.x * 256 + threadIdx.x;
    int bb = blockIdx.y;
    int dirv = blockIdx.z;
    const float* A_log = dirv ? bA : fA;
    const float* Dskip = dirv ? bD : fD;
    const __hip_bfloat16* dtf = dtf2 + (size_t)dirv * MR * DI;
    const __hip_bfloat16* xs = xsb2 + (size_t)dirv * MR * DI;
    const float* xdb = xdb2 + (size_t)dirv * MR * XLD;
    const __hip_bfloat16* xz = xz2 + (size_t)dirv * MR * 2 * DI;
    float Ad[DST], h[DST];
    #pragma unroll
    for (int s = 0; s < DST; ++s) { Ad[s] = -__expf(A_log[d * DST + s]); h[s] = 0.f; }
    float Dsk = Dskip[d];
    for (int i = 0; i < LL; ++i) {
        int t = dirv ? (LL - 1 - i) : i;
        size_t m = (size_t)bb * LL + t;
        float dtv = bf2f(dtf[m * DI + d]);
        float xv  = bf2f(xs[m * DI + d]);
        const float* bc = xdb + m * XLD;
        float dtx = dtv * xv;
        float yv = 0.f;
        #pragma unroll
        for (int s = 0; s < DST; ++s) {
            float dA = __expf(dtv * Ad[s]);
            h[s] = fmaf(h[s], dA, dtx * bc[64 + s]);
            yv = fmaf(h[s], bc[80 + s], yv);
        }
        float zv = bf2f(xz[m * (2 * DI) + DI + d]);
        ycat[m * (2 * DI) + (size_t)dirv * DI + d] =
            __float2bfloat16((yv + xv * Dsk) * siluf(zv));
    }
}

// ---------------- Launch ----------------
extern "C" void kernel_launch(void* const* d_in, const int* in_sizes, int n_in,
                              void* d_out, int out_size, void* d_ws, size_t ws_size,
                              hipStream_t stream)
{
    const float* x      = (const float*)d_in[0];
    const float* ln_w   = (const float*)d_in[1];
    const float* ln_b   = (const float*)d_in[2];
    const float* f_inW    = (const float*)d_in[3];
    const float* f_convW  = (const float*)d_in[4];
    const float* f_convb  = (const float*)d_in[5];
    const float* f_xprojW = (const float*)d_in[6];
    const float* f_dtW    = (const float*)d_in[7];
    const float* f_dtb    = (const float*)d_in[8];
    const float* f_A_log  = (const float*)d_in[9];
    const float* f_Dskip  = (const float*)d_in[10];
    const float* f_outW   = (const float*)d_in[11];
    const float* b_inW    = (const float*)d_in[12];
    const float* b_convW  = (const float*)d_in[13];
    const float* b_convb  = (const float*)d_in[14];
    const float* b_xprojW = (const float*)d_in[15];
    const float* b_dtW    = (const float*)d_in[16];
    const float* b_dtb    = (const float*)d_in[17];
    const float* b_A_log  = (const float*)d_in[18];
    const float* b_Dskip  = (const float*)d_in[19];
    const float* b_outW   = (const float*)d_in[20];
    const float* proj_W = (const float*)d_in[21];
    const float* proj_b = (const float*)d_in[22];

    float* ws = (float*)d_ws;
    size_t o = 0;
    __hip_bfloat16* xz2  = (__hip_bfloat16*)(ws + o);
    o += (size_t)2 * MR * 2 * DI / 2;
    __hip_bfloat16* xsb2 = (__hip_bfloat16*)(ws + o); o += (size_t)2 * MR * DI / 2;
    __hip_bfloat16* ycat = (__hip_bfloat16*)(ws + o);
    o += (size_t)MR * 2 * DI / 2;
    float* xdb2 = ws + o; o += (size_t)2 * MR * XLD;
    __hip_bfloat16* xdbt = (__hip_bfloat16*)(ws + o); o += (size_t)2 * MR * 64 / 2;
    __hip_bfloat16* dtfb = (__hip_bfloat16*)(ws + o); o += (size_t)2 * MR * DI / 2;
    __hip_bfloat16* nb = (__hip_bfloat16*)(ws + o); o += (size_t)MR * DM / 2;
    __hip_bfloat16* warena = (__hip_bfloat16*)(ws + o); o += 15466496 / 2;
    float* hbuf = ws + o;
    size_t base_floats = o;

    __hip_bfloat16* wbi  = warena;               // [2][2DI][DM]    8,388,608
    __hip_bfloat16* pwb  = warena +  8388608;    // [DM][2DM]       2,097,152
    __hip_bfloat16* wdt  = warena + 10485760;    // [2][DI][64]       262,144
    __hip_bfloat16* wpb2 = warena + 10747904;    // [2][128][DI]      524,288
    __hip_bfloat16* wcat = warena + 11272192;    // [DM][2DI]       4,194,304

    const size_t slab = (size_t)NB * DI * DST;   // 65536
    int G = 32;
    while (G > 4 && (base_floats + 4ull * G * slab) * 4 > ws_size) G >>= 1;
    int useChunks = ((base_floats + 4ull * G * slab) * 4 <= ws_size);
    float* hend  = hbuf;
    float* aprod = hbuf + 2ull * G * slab;
    int Cn = useChunks ? LL / G : LL;

    // wot [2][DI][DM] bf16: in hbuf when chunked; else aliases xz2 (Wcat first).
    int wotInHbuf = useChunks && (4ull * G * slab >= 2097152ull);
    __hip_bfloat16* wot = wotInHbuf ? (__hip_bfloat16*)hbuf : xz2;

    // 1: mega-prep (weight cvts + transpose + layernorm)
    prep_k<<<5824, 256, 0, stream>>>(
        f_inW, b_inW, proj_W, f_dtW, b_dtW, warena,
        f_xprojW, b_xprojW, wpb2,
        f_outW, b_outW, wot,
        x, ln_w, ln_b, nb);

    // 2-3: in-proj, then merged conv+wcat (independent work, one dispatch)
    if (wotInHbuf) {
        inproj256_k<<<256, 512, 0, stream>>>(nb, wbi, xz2);
        conv_wcat_k<<<1280, 256, 0, stream>>>(
            xz2, f_convW, f_convb, b_convW, b_convb, xsb2, pwb, wot, wcat);
    } else {
        gemm_gl<1><<<dim3(DI / 128, DM / 128, 2), 256, 0, stream>>>(
            pwb, 2 * DM, (size_t)DM, wot, DM, (size_t)DI * DM,
            wcat, 2 * DI, (size_t)DI, DM, nullptr, nullptr);
        inproj256_k<<<256, 512, 0, stream>>>(nb, wbi, xz2);
        conv_silu_k<<<dim3(MR / 4, 2), 256, 0, stream>>>(
            xz2, f_convW, f_convb, b_convW, b_convb, xsb2);
    }

    // 4: x-proj direct (full-K, no partials)
    xproj64_k<<<dim3(MR / 32, 2), 256, 0, stream>>>(xsb2, wpb2, xdb2, xdbt);

    // 5: dt-proj both dirs: dtfb = softplus(xdbt @ dtW^T + dtb) (bf16)
    gemm_gl<3><<<dim3(DI / 128, MR / 128, 2), 256, 0, stream>>>(
        xdbt, 64, (size_t)MR * 64, wdt, 64, (size_t)DI * 64,
        dtfb, DI, (size_t)MR * DI, 64, f_dtb, b_dtb);

    // 6-8: selective scan both dirs -> ycat [MR][2*DI]  (3-dispatch, proven)
    if (useChunks) {
        scan1_k<<<dim3(DI / 256, NB, 2 * G), 256, 0, stream>>>(
            dtfb, xsb2, xdb2, f_A_log, b_A_log, hend, aprod, G, Cn);
        scan2_k<<<dim3((NB * DI * DST) / 256, 2), 256, 0, stream>>>(hend, aprod, G);
        scan3_k<<<dim3(DI / 256, NB, 2 * G), 256, 0, stream>>>(
            dtfb, xsb2, xdb2, xz2, f_A_log, b_A_log, f_Dskip, b_Dskip,
            hend, ycat, G, Cn);
    } else {
        scan_mono_k<<<dim3(DI / 256, NB, 2), 256, 0, stream>>>(
            dtfb, xsb2, xdb2, xz2, f_A_log, b_A_log, f_Dskip, b_Dskip, ycat);
    }

    // 9: fused out-proj: out = x + proj_b + ycat @ wcat^T
    outproj_k<<<dim3(DM / 64, MR / 64), 256, 0, stream>>>(
        ycat, wcat, x, proj_b, (float*)d_out);
}

// Round 10
// 386.791 us; speedup vs baseline: 1.0453x; 1.0453x over previous
//
#include <hip/hip_runtime.h>
#include <hip/hip_bf16.h>
#include <math.h>

#define DM   1024   // d_model
#define DI   2048   // d_inner
#define DTR  64     // dt_rank
#define DST  16     // d_state
#define NB   2      // batch
#define LL   1024   // seq len
#define MR   (NB*LL)  // 2048 rows
#define XLD  128    // xdb padded leading dim
#define KS   8      // split-K factor for x-proj

typedef __bf16 bf16x8 __attribute__((ext_vector_type(8)));
typedef float  f32x4  __attribute__((ext_vector_type(4)));
typedef unsigned short u16x8 __attribute__((ext_vector_type(8)));

__device__ __forceinline__ float siluf(float x) { return x / (1.f + __expf(-x)); }
__device__ __forceinline__ float softplusf(float x) {
    return fmaxf(x, 0.f) + log1pf(__expf(-fabsf(x)));
}
__device__ __forceinline__ unsigned short f2bf(float f) {
    __hip_bfloat16 h = __float2bfloat16(f);
    return *reinterpret_cast<unsigned short*>(&h);
}
__device__ __forceinline__ float bf2f(__hip_bfloat16 h) { return __bfloat162float(h); }
__device__ __forceinline__ float bfu2f(unsigned short u) {
    __hip_bfloat16 h = *reinterpret_cast<__hip_bfloat16*>(&u);
    return __bfloat162float(h);
}

__device__ __forceinline__ void gl2lds16(const __hip_bfloat16* g, __hip_bfloat16* l)
{
    __builtin_amdgcn_global_load_lds(
        (const __attribute__((address_space(1))) unsigned int*)g,
        (__attribute__((address_space(3))) unsigned int*)l, 16, 0, 0);
}

// ---------------- mega-prep: weight cvts + transpose + layernorm ----------------
__global__ __launch_bounds__(256) void prep_k(
    const float* __restrict__ s0, const float* __restrict__ s1,
    const float* __restrict__ s2, const float* __restrict__ s3,
    const float* __restrict__ s4, __hip_bfloat16* __restrict__ warena,
    const float* __restrict__ fx, const float* __restrict__ bx,
    __hip_bfloat16* __restrict__ wpb2,
    const float* __restrict__ fo, const float* __restrict__ bo,
    __hip_bfloat16* __restrict__ wot,
    const float* __restrict__ x, const float* __restrict__ lnw,
    const float* __restrict__ lnb, __hip_bfloat16* __restrict__ nb)
{
    __shared__ float pshm[64 * 65];
    const int b = blockIdx.x;
    const int tid = threadIdx.x;

    if (b < 2624) {
        long base = (long)b * 4096;
        const float* src; long off;
        if      (base <  4194304L) { src = s0; off = base; }
        else if (base <  8388608L) { src = s1; off = base -  4194304L; }
        else if (base < 10485760L) { src = s2; off = base -  8388608L; }
        else if (base < 10616832L) { src = s3; off = base - 10485760L; }
        else                       { src = s4; off = base - 10616832L; }
        #pragma unroll
        for (int j = 0; j < 4; ++j) {
            long e = (long)j * 1024 + tid * 4;
            float4 v = *(const float4*)(src + off + e);
            ushort4 o;
            o.x = f2bf(v.x); o.y = f2bf(v.y); o.z = f2bf(v.z); o.w = f2bf(v.w);
            *(ushort4*)((unsigned short*)warena + base + e) = o;
        }
    } else if (b < 2752) {
        int t = b - 2624;
        int z = t >> 6;
        const float* in = z ? bx : fx;
        int idx = ((t & 63) * 256 + tid) * 4;   // over 128*DI
        int row = idx >> 11;
        ushort4 o = make_ushort4(0, 0, 0, 0);
        if (row < 96) {
            float4 v = *(const float4*)(in + idx);
            o.x = f2bf(v.x); o.y = f2bf(v.y); o.z = f2bf(v.z); o.w = f2bf(v.w);
        }
        *(ushort4*)((unsigned short*)wpb2 + (size_t)z * 128 * DI + idx) = o;
    } else if (b < 3776) {
        int t = b - 2752;
        int z = t >> 9; t &= 511;
        const float* src = z ? bo : fo;
        int c0 = (t & 31) * 64;    // col in src (DI dim)
        int r0 = (t >> 5) * 64;    // row in src (DM dim)
        int tc = tid & 63;
        int tr = tid >> 6;
        #pragma unroll
        for (int ii = 0; ii < 16; ++ii) {
            int rl = tr + ii * 4;
            pshm[tc * 65 + rl] = src[(size_t)(r0 + rl) * DI + c0 + tc];
        }
        __syncthreads();
        __hip_bfloat16* dst = wot + (size_t)z * DI * DM;
        #pragma unroll
        for (int ii = 0; ii < 16; ++ii) {
            int cl = tr + ii * 4;
            dst[(size_t)(c0 + cl) * DM + r0 + tc] = __float2bfloat16(pshm[cl * 65 + tc]);
        }
    } else {
        int row = b - 3776;
        const float* xr = x + (size_t)row * DM;
        float4 v = *(const float4*)(xr + tid * 4);
        float s = v.x + v.y + v.z + v.w;
        float q = v.x*v.x + v.y*v.y + v.z*v.z + v.w*v.w;
        #pragma unroll
        for (int off = 32; off > 0; off >>= 1) {
            s += __shfl_xor(s, off, 64);
            q += __shfl_xor(q, off, 64);
        }
        int wv = tid >> 6;
        if ((tid & 63) == 0) { pshm[wv] = s; pshm[8 + wv] = q; }
        __syncthreads();
        s = pshm[0] + pshm[1] + pshm[2] + pshm[3];
        q = pshm[8] + pshm[9] + pshm[10] + pshm[11];
        float mu  = s * (1.f / DM);
        float var = q * (1.f / DM) - mu * mu;
        float rstd = rsqrtf(var + 1e-5f);
        float4 wv4 = *(const float4*)(lnw + tid * 4);
        float4 bv4 = *(const float4*)(lnb + tid * 4);
        ushort4 o;
        o.x = f2bf((v.x - mu) * rstd * wv4.x + bv4.x);
        o.y = f2bf((v.y - mu) * rstd * wv4.y + bv4.y);
        o.z = f2bf((v.z - mu) * rstd * wv4.z + bv4.z);
        o.w = f2bf((v.w - mu) * rstd * wv4.w + bv4.w);
        *(ushort4*)((unsigned short*)nb + (size_t)row * DM + tid * 4) = o;
    }
}

// ---------------- in-proj: 256x256, BK=64, 4-phase/tile ----------------
__global__ __launch_bounds__(512) void inproj256_k(
    const __hip_bfloat16* __restrict__ A,
    const __hip_bfloat16* __restrict__ Bmat,
    __hip_bfloat16* __restrict__ C)
{
    __shared__ __hip_bfloat16 smem[65536];   // 128 KiB
    const int tid = threadIdx.x;
    int id = blockIdx.x;
    int s  = (id & 7) * 32 + (id >> 3);
    const int z  = s >> 7;
    const int r  = s & 127;
    const int bm = (r & 7) * 256;
    const int bn = (r >> 3) * 256;
    const __hip_bfloat16* Az = A;
    const __hip_bfloat16* Bz = Bmat + (size_t)z * 2 * DI * DM;
    __hip_bfloat16* Cz = C + (size_t)z * MR * 2 * DI;

    const int wv   = tid >> 6;
    const int lane = tid & 63;
    const int wm   = wv >> 2;      // 0..1
    const int wn   = wv & 3;       // 0..3
    const int fr   = lane & 15;
    const int quad = lane >> 4;

    const int srow = tid >> 2;                       // 0..127
    const int scol = 8 * ((tid & 3) ^ ((tid >> 3) & 3));
    const int kph  = (quad ^ ((fr >> 1) & 3)) * 8;

    __hip_bfloat16* const Asl = smem;          // [2][2][256][32]
    __hip_bfloat16* const Bsl = smem + 32768;

    f32x4 acc[8][4] = {};
    bf16x8 aF[4], bB[4];

#define STG_A(TAU, KK) { \
    const int ub_ = (((TAU) & 1) * 2 + (KK)) * 8192; \
    const int gc_ = (TAU) * 64 + (KK) * 32 + scol; \
    gl2lds16(Az + (size_t)(bm + srow) * DM + gc_,       Asl + ub_ + tid * 8); \
    gl2lds16(Az + (size_t)(bm + 128 + srow) * DM + gc_, Asl + ub_ + 4096 + tid * 8); }
#define STG_B(TAU, KK) { \
    const int ub_ = (((TAU) & 1) * 2 + (KK)) * 8192; \
    const int gc_ = (TAU) * 64 + (KK) * 32 + scol; \
    gl2lds16(Bz + (size_t)(bn + srow) * DM + gc_,       Bsl + ub_ + tid * 8); \
    gl2lds16(Bz + (size_t)(bn + 128 + srow) * DM + gc_, Bsl + ub_ + 4096 + tid * 8); }

#define RD_A(BUF, KK, MH) { \
    const __hip_bfloat16* p_ = Asl + ((BUF) * 2 + (KK)) * 8192 + kph; \
    _Pragma("unroll") for (int i = 0; i < 4; ++i) \
        aF[i] = *(const bf16x8*)(p_ + (wm * 128 + (MH) * 64 + i * 16 + fr) * 32); }
#define RD_B(BUF, KK) { \
    const __hip_bfloat16* p_ = Bsl + ((BUF) * 2 + (KK)) * 8192 + kph; \
    _Pragma("unroll") for (int j = 0; j < 4; ++j) \
        bB[j] = *(const bf16x8*)(p_ + (wn * 64 + j * 16 + fr) * 32); }

#define PHASE(BUF, KK, MH, STGC, T1, T2, VMC) { \
    if ((MH) == 0) { RD_B(BUF, KK); } \
    RD_A(BUF, KK, MH); \
    if ((STGC) == 1) { STG_A((T1), 1); } \
    if ((STGC) == 2) { STG_B((T1), 1); } \
    if ((STGC) == 3) { STG_A((T2), 0); } \
    if ((STGC) == 4) { STG_B((T2), 0); } \
    asm volatile("s_barrier" ::: "memory"); \
    asm volatile("s_waitcnt lgkmcnt(0)" ::: "memory"); \
    __builtin_amdgcn_sched_barrier(0); \
    __builtin_amdgcn_s_setprio(1); \
    _Pragma("unroll") for (int i = 0; i < 4; ++i) \
        _Pragma("unroll") for (int j = 0; j < 4; ++j) \
            acc[(MH) * 4 + i][j] = __builtin_amdgcn_mfma_f32_16x16x32_bf16( \
                aF[i], bB[j], acc[(MH) * 4 + i][j], 0, 0, 0); \
    __builtin_amdgcn_s_setprio(0); \
    if ((VMC) == 8) { asm volatile("s_waitcnt vmcnt(8)" ::: "memory"); } \
    if ((VMC) == 4) { asm volatile("s_waitcnt vmcnt(4)" ::: "memory"); } \
    if ((VMC) == 1) { asm volatile("s_waitcnt vmcnt(0)" ::: "memory"); } \
    asm volatile("s_barrier" ::: "memory"); }

    STG_A(0, 0); STG_B(0, 0); STG_A(0, 1); STG_B(0, 1); STG_A(1, 0); STG_B(1, 0);
    asm volatile("s_waitcnt vmcnt(8)" ::: "memory");
    asm volatile("s_barrier" ::: "memory");

    #pragma unroll 1
    for (int t = 0; t < 14; ++t) {
        const int buf = t & 1;
        const int t1 = t + 1, t2 = t + 2;
        PHASE(buf, 0, 0, 1, t1, t2, 0);
        PHASE(buf, 0, 1, 2, t1, t2, 8);
        PHASE(buf, 1, 0, 3, t1, t2, 0);
        PHASE(buf, 1, 1, 4, t1, t2, 8);
    }
    PHASE(0, 0, 0, 1, 15, 0, 0);
    PHASE(0, 0, 1, 2, 15, 0, 8);
    PHASE(0, 1, 0, 0, 0, 0, 0);
    PHASE(0, 1, 1, 0, 0, 0, 4);
    PHASE(1, 0, 0, 0, 0, 0, 0);
    PHASE(1, 0, 1, 0, 0, 0, 1);
    PHASE(1, 1, 0, 0, 0, 0, 0);
    PHASE(1, 1, 1, 0, 0, 0, 0);

#undef PHASE
#undef RD_A
#undef RD_B
#undef STG_A
#undef STG_B

    // epilogue: 4 passes of 64 rows via LDS restage -> 64 B/thread stores
    float* eps = (float*)smem;
    const int orow = tid >> 3;          // 0..63
    const int ocol = (tid & 7) * 32;    // 0..224
    #pragma unroll
    for (int p = 0; p < 4; ++p) {
        __syncthreads();
        if (wm == (p >> 1)) {
            int ib = (p & 1) * 4;
            #pragma unroll
            for (int i2 = 0; i2 < 4; ++i2)
                #pragma unroll
                for (int j = 0; j < 4; ++j)
                    #pragma unroll
                    for (int rr = 0; rr < 4; ++rr)
                        eps[(i2 * 16 + quad * 4 + rr) * 260 + wn * 64 + j * 16 + fr]
                            = acc[ib + i2][j][rr];
        }
        __syncthreads();
        unsigned short os[32] __attribute__((aligned(16)));
        #pragma unroll
        for (int c = 0; c < 32; ++c) os[c] = f2bf(eps[orow * 260 + ocol + c]);
        unsigned short* dst = (unsigned short*)Cz +
            (size_t)(bm + p * 64 + orow) * (2 * DI) + bn + ocol;
        *(uint4*)(dst +  0) = *(const uint4*)(os +  0);
        *(uint4*)(dst +  8) = *(const uint4*)(os +  8);
        *(uint4*)(dst + 16) = *(const uint4*)(os + 16);
        *(uint4*)(dst + 24) = *(const uint4*)(os + 24);
    }
}

// ---------------- bf16 MFMA GEMM with global_load_lds staging ----------------
// EPI: 1 = bf16 store, 3 = softplus(v+bias_z[n]) bf16 store.
template<int EPI>
__global__ __launch_bounds__(256) void gemm_gl(
    const __hip_bfloat16* __restrict__ A, int lda, size_t aofs,
    const __hip_bfloat16* __restrict__ B, int ldb, size_t bofs,
    void* __restrict__ Cp, int ldc, size_t cofs, int K,
    const float* __restrict__ bias0, const float* __restrict__ bias1)
{
    __shared__ __hip_bfloat16 smem[2 * 128 * 64];
    __hip_bfloat16* As = smem;
    __hip_bfloat16* Bs = smem + 128 * 64;
    const int tid  = threadIdx.x;
    const int z    = blockIdx.z;
    const int bm   = blockIdx.y * 128;
    const int bn   = blockIdx.x * 128;
    const __hip_bfloat16* Az = A + (size_t)z * aofs;
    const __hip_bfloat16* Bz = B + (size_t)z * bofs;
    const int wv   = tid >> 6;
    const int lane = tid & 63;
    const int wr   = (wv >> 1) * 64;
    const int wc   = (wv & 1) * 64;
    const int srow = wv * 32 + (lane >> 3);
    const int cg   = ((lane & 7) ^ (lane >> 3)) * 8;
    const int fr   = lane & 15;
    const int quad = lane >> 4;
    const int pc0  = (quad ^ (fr & 7)) * 8;
    const int pc1  = ((4 + quad) ^ (fr & 7)) * 8;

    f32x4 acc[4][4] = {};

    for (int k0 = 0; k0 < K; k0 += 64) {
        __syncthreads();
        #pragma unroll
        for (int i = 0; i < 4; ++i) {
            int r = srow + i * 8;
            gl2lds16(Az + (size_t)(bm + r) * lda + k0 + cg, As + wv * 2048 + i * 512);
            gl2lds16(Bz + (size_t)(bn + r) * ldb + k0 + cg, Bs + wv * 2048 + i * 512);
        }
        __syncthreads();
        #pragma unroll
        for (int kk = 0; kk < 2; ++kk) {
            const int pc = kk ? pc1 : pc0;
            bf16x8 af[4], bf_[4];
            #pragma unroll
            for (int i = 0; i < 4; ++i) {
                af[i]  = *(const bf16x8*)(As + (wr + i * 16 + fr) * 64 + pc);
                bf_[i] = *(const bf16x8*)(Bs + (wc + i * 16 + fr) * 64 + pc);
            }
            #pragma unroll
            for (int i = 0; i < 4; ++i)
                #pragma unroll
                for (int j = 0; j < 4; ++j)
                    acc[i][j] = __builtin_amdgcn_mfma_f32_16x16x32_bf16(
                        af[i], bf_[j], acc[i][j], 0, 0, 0);
        }
    }

    const float* bias = (EPI == 3) ? (z ? bias1 : bias0) : nullptr;
    float* eps = (float*)smem;
    const int half = wv >> 1;
    const int lrow = tid >> 3;
    const int cseg = (tid & 7) * 16;
    const int gr_  = bm + (lrow >> 4) * 64 + (lrow & 15);
    #pragma unroll
    for (int i = 0; i < 4; ++i) {
        __syncthreads();
        #pragma unroll
        for (int j = 0; j < 4; ++j)
            #pragma unroll
            for (int r = 0; r < 4; ++r)
                eps[(half * 16 + quad * 4 + r) * 132 + wc + j * 16 + fr] = acc[i][j][r];
        __syncthreads();
        float vals[16];
        *(float4*)(vals +  0) = *(const float4*)(eps + lrow * 132 + cseg +  0);
        *(float4*)(vals +  4) = *(const float4*)(eps + lrow * 132 + cseg +  4);
        *(float4*)(vals +  8) = *(const float4*)(eps + lrow * 132 + cseg +  8);
        *(float4*)(vals + 12) = *(const float4*)(eps + lrow * 132 + cseg + 12);
        int gr = gr_ + i * 16;
        int gc = bn + cseg;
        unsigned short os[16];
        #pragma unroll
        for (int c = 0; c < 16; ++c) {
            float t = vals[c];
            if (EPI == 3) t = softplusf(t + bias[gc + c]);
            os[c] = f2bf(t);
        }
        unsigned short* dst = (unsigned short*)Cp + (size_t)z * cofs +
                              (size_t)gr * ldc + gc;
        *(ushort4*)(dst +  0) = *(ushort4*)(os +  0);
        *(ushort4*)(dst +  4) = *(ushort4*)(os +  4);
        *(ushort4*)(dst +  8) = *(ushort4*)(os +  8);
        *(ushort4*)(dst + 12) = *(ushort4*)(os + 12);
    }
}

// ---------------- merged conv+silu (blocks 0..1023) + Wcat gemm (1024..1279) ----------------
__global__ __launch_bounds__(256) void conv_wcat_k(
    const __hip_bfloat16* __restrict__ xz2,
    const float* __restrict__ fW, const float* __restrict__ fb,
    const float* __restrict__ bW, const float* __restrict__ bb_,
    __hip_bfloat16* __restrict__ xsb2,
    const __hip_bfloat16* __restrict__ pwb,
    const __hip_bfloat16* __restrict__ wot,
    __hip_bfloat16* __restrict__ wcat)
{
    __shared__ __hip_bfloat16 smem[2 * 128 * 64];
    const int b   = blockIdx.x;
    const int tid = threadIdx.x;

    if (b < 1024) {
        // ---- conv branch ----
        const int dirv  = b >> 9;
        const int chunk = b & 511;
        const int bb    = chunk >> 8;
        const int t0    = (chunk & 255) * 4;
        const int d     = tid * 8;

        const float* w    = (dirv ? bW : fW) + d * 4;
        const float* bias = (dirv ? bb_ : fb) + d;
        const unsigned short* xz =
            (const unsigned short*)(xz2 + (size_t)dirv * MR * 2 * DI) + d;

        u16x8 rows[7];
        #pragma unroll
        for (int rr = 0; rr < 7; ++rr) {
            int t = dirv ? (t0 + rr) : (t0 - 3 + rr);
            bool ok = dirv ? (t < LL) : (t >= 0);
            u16x8 v = {};
            if (ok) v = *(const u16x8*)(xz + (size_t)(bb * LL + t) * (2 * DI));
            rows[rr] = v;
        }
        float wq[8][4];
        #pragma unroll
        for (int c = 0; c < 8; ++c) {
            float4 t = *(const float4*)(w + c * 4);
            if (dirv) { wq[c][0]=t.w; wq[c][1]=t.z; wq[c][2]=t.y; wq[c][3]=t.x; }
            else      { wq[c][0]=t.x; wq[c][1]=t.y; wq[c][2]=t.z; wq[c][3]=t.w; }
        }
        float4 b0 = *(const float4*)(bias);
        float4 b1 = *(const float4*)(bias + 4);
        float bs[8] = {b0.x, b0.y, b0.z, b0.w, b1.x, b1.y, b1.z, b1.w};

        unsigned short* outp = (unsigned short*)xsb2 + (size_t)dirv * MR * DI +
                               (size_t)(bb * LL + t0) * DI + d;
        #pragma unroll
        for (int o = 0; o < 4; ++o) {
            unsigned short os[8] __attribute__((aligned(16)));
            #pragma unroll
            for (int c = 0; c < 8; ++c) {
                float a = bs[c];
                #pragma unroll
                for (int k = 0; k < 4; ++k)
                    a = fmaf(wq[c][k], bfu2f(rows[o + k][c]), a);
                os[c] = f2bf(siluf(a));
            }
            *(uint4*)(outp + (size_t)o * DI) = *(const uint4*)os;
        }
        return;
    }

    // ---- wcat branch: gemm body, lda=2*DM, ldb=DM, ldc=2*DI, K=DM ----
    const int t_   = b - 1024;
    const int bn   = (t_ & 15) * 128;         // over DI cols
    const int bm   = ((t_ >> 4) & 7) * 128;   // over DM rows
    const int z    = t_ >> 7;                 // dir
    const __hip_bfloat16* Az = pwb + (size_t)z * DM;
    const __hip_bfloat16* Bz = wot + (size_t)z * DI * DM;
    __hip_bfloat16* As = smem;
    __hip_bfloat16* Bs = smem + 128 * 64;
    const int wv   = tid >> 6;
    const int lane = tid & 63;
    const int wr   = (wv >> 1) * 64;
    const int wc   = (wv & 1) * 64;
    const int srow = wv * 32 + (lane >> 3);
    const int cg   = ((lane & 7) ^ (lane >> 3)) * 8;
    const int fr   = lane & 15;
    const int quad = lane >> 4;
    const int pc0  = (quad ^ (fr & 7)) * 8;
    const int pc1  = ((4 + quad) ^ (fr & 7)) * 8;

    f32x4 acc[4][4] = {};

    for (int k0 = 0; k0 < DM; k0 += 64) {
        __syncthreads();
        #pragma unroll
        for (int i = 0; i < 4; ++i) {
            int r = srow + i * 8;
            gl2lds16(Az + (size_t)(bm + r) * (2 * DM) + k0 + cg, As + wv * 2048 + i * 512);
            gl2lds16(Bz + (size_t)(bn + r) * DM + k0 + cg,       Bs + wv * 2048 + i * 512);
        }
        __syncthreads();
        #pragma unroll
        for (int kk = 0; kk < 2; ++kk) {
            const int pc = kk ? pc1 : pc0;
            bf16x8 af[4], bf_[4];
            #pragma unroll
            for (int i = 0; i < 4; ++i) {
                af[i]  = *(const bf16x8*)(As + (wr + i * 16 + fr) * 64 + pc);
                bf_[i] = *(const bf16x8*)(Bs + (wc + i * 16 + fr) * 64 + pc);
            }
            #pragma unroll
            for (int i = 0; i < 4; ++i)
                #pragma unroll
                for (int j = 0; j < 4; ++j)
                    acc[i][j] = __builtin_amdgcn_mfma_f32_16x16x32_bf16(
                        af[i], bf_[j], acc[i][j], 0, 0, 0);
        }
    }

    float* eps = (float*)smem;
    const int half = wv >> 1;
    const int lrow = tid >> 3;
    const int cseg = (tid & 7) * 16;
    const int gr_  = bm + (lrow >> 4) * 64 + (lrow & 15);
    #pragma unroll
    for (int i = 0; i < 4; ++i) {
        __syncthreads();
        #pragma unroll
        for (int j = 0; j < 4; ++j)
            #pragma unroll
            for (int r = 0; r < 4; ++r)
                eps[(half * 16 + quad * 4 + r) * 132 + wc + j * 16 + fr] = acc[i][j][r];
        __syncthreads();
        float vals[16];
        *(float4*)(vals +  0) = *(const float4*)(eps + lrow * 132 + cseg +  0);
        *(float4*)(vals +  4) = *(const float4*)(eps + lrow * 132 + cseg +  4);
        *(float4*)(vals +  8) = *(const float4*)(eps + lrow * 132 + cseg +  8);
        *(float4*)(vals + 12) = *(const float4*)(eps + lrow * 132 + cseg + 12);
        int gr = gr_ + i * 16;
        int gc = bn + cseg;
        unsigned short os[16];
        #pragma unroll
        for (int c = 0; c < 16; ++c) os[c] = f2bf(vals[c]);
        unsigned short* dst = (unsigned short*)wcat + (size_t)z * DI +
                              (size_t)gr * (2 * DI) + gc;
        *(ushort4*)(dst +  0) = *(ushort4*)(os +  0);
        *(ushort4*)(dst +  4) = *(ushort4*)(os +  4);
        *(ushort4*)(dst +  8) = *(ushort4*)(os +  8);
        *(ushort4*)(dst + 12) = *(ushort4*)(os + 12);
    }
}

// ---------------- fused out-proj: out = x + proj_b + ycat @ wcat^T ----------------
__global__ __launch_bounds__(256) void outproj_k(
    const __hip_bfloat16* __restrict__ A,   // ycat [MR][4096]
    const __hip_bfloat16* __restrict__ Bm,  // wcat [DM][4096]
    const float* __restrict__ x, const float* __restrict__ proj_b,
    float* __restrict__ out)
{
    __shared__ __hip_bfloat16 smem[2 * 64 * 64];
    __hip_bfloat16* As = smem;
    __hip_bfloat16* Bs = smem + 64 * 64;
    const int tid  = threadIdx.x;
    const int bn   = blockIdx.x * 64;
    const int bm   = blockIdx.y * 64;
    const int wv   = tid >> 6;
    const int lane = tid & 63;
    const int wr   = (wv >> 1) * 32;
    const int wc   = (wv & 1) * 32;
    const int srow = wv * 16 + (lane >> 3);
    const int cg   = ((lane & 7) ^ (lane >> 3)) * 8;
    const int fr   = lane & 15;
    const int quad = lane >> 4;
    const int pc0  = (quad ^ (fr & 7)) * 8;
    const int pc1  = ((4 + quad) ^ (fr & 7)) * 8;
    const int K    = 2 * DI;

    f32x4 acc[2][2] = {};

    for (int k0 = 0; k0 < K; k0 += 64) {
        __syncthreads();
        #pragma unroll
        for (int j = 0; j < 2; ++j) {
            int r = srow + j * 8;
            gl2lds16(A  + (size_t)(bm + r) * K + k0 + cg, As + wv * 1024 + j * 512);
            gl2lds16(Bm + (size_t)(bn + r) * K + k0 + cg, Bs + wv * 1024 + j * 512);
        }
        __syncthreads();
        #pragma unroll
        for (int kk = 0; kk < 2; ++kk) {
            const int pc = kk ? pc1 : pc0;
            bf16x8 af[2], bf_[2];
            #pragma unroll
            for (int i = 0; i < 2; ++i) {
                af[i]  = *(const bf16x8*)(As + (wr + i * 16 + fr) * 64 + pc);
                bf_[i] = *(const bf16x8*)(Bs + (wc + i * 16 + fr) * 64 + pc);
            }
            #pragma unroll
            for (int i = 0; i < 2; ++i)
                #pragma unroll
                for (int j = 0; j < 2; ++j)
                    acc[i][j] = __builtin_amdgcn_mfma_f32_16x16x32_bf16(
                        af[i], bf_[j], acc[i][j], 0, 0, 0);
        }
    }

    const float pb0 = proj_b[bn + wc + fr];
    const float pb1 = proj_b[bn + wc + 16 + fr];
    #pragma unroll
    for (int i = 0; i < 2; ++i)
        #pragma unroll
        for (int j = 0; j < 2; ++j) {
            const int gc = bn + wc + j * 16 + fr;
            const float pb = j ? pb1 : pb0;
            #pragma unroll
            for (int r = 0; r < 4; ++r) {
                size_t off = (size_t)(bm + wr + i * 16 + quad * 4 + r) * DM + gc;
                out[off] = x[off] + pb + acc[i][j][r];
            }
        }
}

// ---------------- x-proj split-K partials, grouped over dir ----------------
__global__ __launch_bounds__(256) void xproj_part_k(
    const __hip_bfloat16* __restrict__ A,
    const __hip_bfloat16* __restrict__ B,
    float* __restrict__ part)
{
    __shared__ __hip_bfloat16 smem[2 * 128 * 64];
    __hip_bfloat16* As = smem;
    __hip_bfloat16* Bs = smem + 128 * 64;
    const int tid  = threadIdx.x;
    const int ks   = blockIdx.x;
    const int bm   = blockIdx.y * 128;
    const int z    = blockIdx.z;
    const __hip_bfloat16* Az = A + (size_t)z * MR * DI;
    const __hip_bfloat16* Bz = B + (size_t)z * 128 * DI;
    const int kb   = ks * (DI / KS);
    const int wv   = tid >> 6;
    const int lane = tid & 63;
    const int wr   = (wv >> 1) * 64;
    const int wc   = (wv & 1) * 64;
    const int srow = wv * 32 + (lane >> 3);
    const int cg   = ((lane & 7) ^ (lane >> 3)) * 8;
    const int fr   = lane & 15;
    const int quad = lane >> 4;
    const int pc0  = (quad ^ (fr & 7)) * 8;
    const int pc1  = ((4 + quad) ^ (fr & 7)) * 8;

    f32x4 acc[4][4] = {};

    #pragma unroll
    for (int k0 = 0; k0 < DI / KS; k0 += 64) {
        __syncthreads();
        #pragma unroll
        for (int i = 0; i < 4; ++i) {
            int r = srow + i * 8;
            gl2lds16(Az + (size_t)(bm + r) * DI + kb + k0 + cg, As + wv * 2048 + i * 512);
            gl2lds16(Bz + (size_t)r * DI + kb + k0 + cg,        Bs + wv * 2048 + i * 512);
        }
        __syncthreads();
        #pragma unroll
        for (int kk = 0; kk < 2; ++kk) {
            const int pc = kk ? pc1 : pc0;
            bf16x8 af[4], bf_[4];
            #pragma unroll
            for (int i = 0; i < 4; ++i) {
                af[i]  = *(const bf16x8*)(As + (wr + i * 16 + fr) * 64 + pc);
                bf_[i] = *(const bf16x8*)(Bs + (wc + i * 16 + fr) * 64 + pc);
            }
            #pragma unroll
            for (int i = 0; i < 4; ++i)
                #pragma unroll
                for (int j = 0; j < 4; ++j)
                    acc[i][j] = __builtin_amdgcn_mfma_f32_16x16x32_bf16(
                        af[i], bf_[j], acc[i][j], 0, 0, 0);
        }
    }

    float* dst = part + ((size_t)z * KS + ks) * MR * XLD;
    const int er = quad * 4;
    #pragma unroll
    for (int i = 0; i < 4; ++i)
        #pragma unroll
        for (int j = 0; j < 4; ++j) {
            int row = bm + wr + i * 16 + er;
            int col = wc + j * 16 + fr;
            #pragma unroll
            for (int r = 0; r < 4; ++r)
                dst[(size_t)(row + r) * XLD + col] = acc[i][j][r];
        }
}

// ---------------- reduce x-proj partials -> xdb2 fp32 + dt-cols bf16 ----------------
__global__ __launch_bounds__(256) void xproj_reduce_k(
    const float* __restrict__ part, float* __restrict__ xdb,
    __hip_bfloat16* __restrict__ xdbt)
{
    int z = blockIdx.y;
    size_t idx = ((size_t)blockIdx.x * 256 + threadIdx.x) * 4;   // over MR*XLD
    const float* p = part + (size_t)z * KS * MR * XLD;
    float4 s = make_float4(0.f, 0.f, 0.f, 0.f);
    #pragma unroll
    for (int ks = 0; ks < KS; ++ks) {
        float4 v = *(const float4*)(p + (size_t)ks * MR * XLD + idx);
        s.x += v.x; s.y += v.y; s.z += v.z; s.w += v.w;
    }
    *(float4*)(xdb + (size_t)z * MR * XLD + idx) = s;
    int c = (int)(idx & (XLD - 1));
    if (c < 64) {
        size_t m = idx >> 7;
        ushort4 o;
        o.x = f2bf(s.x); o.y = f2bf(s.y); o.z = f2bf(s.z); o.w = f2bf(s.w);
        *(ushort4*)((unsigned short*)xdbt + (size_t)z * MR * 64 + m * 64 + c) = o;
    }
}

// ---------------- conv fallback (wotInHbuf==0 path) ----------------
__global__ __launch_bounds__(256) void conv_silu_k(
    const __hip_bfloat16* __restrict__ xz2,
    const float* __restrict__ fW, const float* __restrict__ fb,
    const float* __restrict__ bW, const float* __restrict__ bb_,
    __hip_bfloat16* __restrict__ xsb2)
{
    const int dirv  = blockIdx.y;
    const int chunk = blockIdx.x;
    const int bb    = chunk >> 8;
    const int t0    = (chunk & 255) * 4;
    const int d     = threadIdx.x * 8;

    const float* w    = (dirv ? bW : fW) + d * 4;
    const float* bias = (dirv ? bb_ : fb) + d;
    const unsigned short* xz =
        (const unsigned short*)(xz2 + (size_t)dirv * MR * 2 * DI) + d;

    u16x8 rows[7];
    #pragma unroll
    for (int rr = 0; rr < 7; ++rr) {
        int t = dirv ? (t0 + rr) : (t0 - 3 + rr);
        bool ok = dirv ? (t < LL) : (t >= 0);
        u16x8 v = {};
        if (ok) v = *(const u16x8*)(xz + (size_t)(bb * LL + t) * (2 * DI));
        rows[rr] = v;
    }
    float wq[8][4];
    #pragma unroll
    for (int c = 0; c < 8; ++c) {
        float4 t = *(const float4*)(w + c * 4);
        if (dirv) { wq[c][0]=t.w; wq[c][1]=t.z; wq[c][2]=t.y; wq[c][3]=t.x; }
        else      { wq[c][0]=t.x; wq[c][1]=t.y; wq[c][2]=t.z; wq[c][3]=t.w; }
    }
    float4 b0 = *(const float4*)(bias);
    float4 b1 = *(const float4*)(bias + 4);
    float bs[8] = {b0.x, b0.y, b0.z, b0.w, b1.x, b1.y, b1.z, b1.w};

    unsigned short* outp = (unsigned short*)xsb2 + (size_t)dirv * MR * DI +
                           (size_t)(bb * LL + t0) * DI + d;
    #pragma unroll
    for (int o = 0; o < 4; ++o) {
        unsigned short os[8] __attribute__((aligned(16)));
        #pragma unroll
        for (int c = 0; c < 8; ++c) {
            float a = bs[c];
            #pragma unroll
            for (int k = 0; k < 4; ++k)
                a = fmaf(wq[c][k], bfu2f(rows[o + k][c]), a);
            os[c] = f2bf(siluf(a));
        }
        *(uint4*)(outp + (size_t)o * DI) = *(const uint4*)os;
    }
}

// ---------------- Chunked selective scan, both dirs (3-dispatch, proven) ----------------
__global__ __launch_bounds__(256) void scan1_k(
    const __hip_bfloat16* __restrict__ dtf2, const __hip_bfloat16* __restrict__ xsb2,
    const float* __restrict__ xdb2,
    const float* __restrict__ fA, const float* __restrict__ bA,
    float* __restrict__ hend, float* __restrict__ aprod, int G, int Cn)
{
    int d  = blockIdx.x * 256 + threadIdx.x;
    int bb = blockIdx.y;
    int zz = blockIdx.z;
    int dirv = (zz >= G) ? 1 : 0;
    int g = zz - (dirv ? G : 0);
    const float* A_log = dirv ? bA : fA;
    const __hip_bfloat16* dtf = dtf2 + (size_t)dirv * MR * DI;
    const __hip_bfloat16* xs = xsb2 + (size_t)dirv * MR * DI;
    const float* xdb = xdb2 + (size_t)dirv * MR * XLD;
    size_t hoff = (size_t)dirv * G * (NB * DI * DST);

    float Ad[DST], h[DST], ap[DST];
    bool pw = true;
    #pragma unroll
    for (int s = 0; s < DST; ++s) {
        Ad[s] = -__expf(A_log[d * DST + s]);
        pw = pw && (fabsf(Ad[s] + (float)(s + 1)) < 1e-3f * (s + 1));
        h[s] = 0.f; ap[s] = 1.f;
    }
    int i0 = g * Cn;
    for (int i = 0; i < Cn; ++i) {
        int ii = i0 + i;
        int t = dirv ? (LL - 1 - ii) : ii;
        size_t m = (size_t)bb * LL + t;
        float dtv = bf2f(dtf[m * DI + d]);
        float xv  = bf2f(xs[m * DI + d]);
        const float* bc = xdb + m * XLD;
        float dtx = dtv * xv;
        float dAv[DST];
        if (pw) {
            float r = __expf(-dtv);
            float a = r;
            #pragma unroll
            for (int s = 0; s < DST; ++s) { dAv[s] = a; a *= r; }
        } else {
            #pragma unroll
            for (int s = 0; s < DST; ++s) dAv[s] = __expf(dtv * Ad[s]);
        }
        #pragma unroll
        for (int s = 0; s < DST; ++s) {
            h[s] = fmaf(h[s], dAv[s], dtx * bc[64 + s]);
            ap[s] *= dAv[s];
        }
    }
    size_t base = hoff + ((size_t)(g * NB + bb) * DI + d) * DST;
    #pragma unroll
    for (int s = 0; s < DST; s += 4) {
        *(float4*)(hend  + base + s) = make_float4(h[s], h[s+1], h[s+2], h[s+3]);
        *(float4*)(aprod + base + s) = make_float4(ap[s], ap[s+1], ap[s+2], ap[s+3]);
    }
}

__global__ __launch_bounds__(256) void scan2_k(
    float* __restrict__ hend, const float* __restrict__ aprod, int G)
{
    int dirv = blockIdx.y;
    int idx = blockIdx.x * 256 + threadIdx.x;
    const int slab = NB * DI * DST;
    size_t hoff = (size_t)dirv * G * slab;
    float carry = 0.f;
    for (int g = 0; g < G; ++g) {
        size_t off = hoff + (size_t)g * slab + idx;
        float a = aprod[off];
        float e = hend[off];
        hend[off] = carry;
        carry = fmaf(a, carry, e);
    }
}

__global__ __launch_bounds__(256) void scan3_k(
    const __hip_bfloat16* __restrict__ dtf2, const __hip_bfloat16* __restrict__ xsb2,
    const float* __restrict__ xdb2, const __hip_bfloat16* __restrict__ xz2,
    const float* __restrict__ fA, const float* __restrict__ bA,
    const float* __restrict__ fD, const float* __restrict__ bD,
    const float* __restrict__ hin, __hip_bfloat16* __restrict__ ycat, int G, int Cn)
{
    int d  = blockIdx.x * 256 + threadIdx.x;
    int bb = blockIdx.y;
    int zz = blockIdx.z;
    int dirv = (zz >= G) ? 1 : 0;
    int g = zz - (dirv ? G : 0);
    const float* A_log = dirv ? bA : fA;
    const float* Dskip = dirv ? bD : fD;
    const __hip_bfloat16* dtf = dtf2 + (size_t)dirv * MR * DI;
    const __hip_bfloat16* xs = xsb2 + (size_t)dirv * MR * DI;
    const float* xdb = xdb2 + (size_t)dirv * MR * XLD;
    const __hip_bfloat16* xz = xz2 + (size_t)dirv * MR * 2 * DI;
    size_t hoff = (size_t)dirv * G * (NB * DI * DST);

    float Ad[DST], h[DST];
    bool pw = true;
    size_t base = hoff + ((size_t)(g * NB + bb) * DI + d) * DST;
    #pragma unroll
    for (int s = 0; s < DST; ++s) {
        Ad[s] = -__expf(A_log[d * DST + s]);
        pw = pw && (fabsf(Ad[s] + (float)(s + 1)) < 1e-3f * (s + 1));
        h[s] = hin[base + s];
    }
    float Dsk = Dskip[d];
    int i0 = g * Cn;
    for (int i = 0; i < Cn; ++i) {
        int ii = i0 + i;
        int t = dirv ? (LL - 1 - ii) : ii;
        size_t m = (size_t)bb * LL + t;
        float dtv = bf2f(dtf[m * DI + d]);
        float xv  = bf2f(xs[m * DI + d]);
        const float* bc = xdb + m * XLD;
        float dtx = dtv * xv;
        float dAv[DST];
        if (pw) {
            float r = __expf(-dtv);
            float a = r;
            #pragma unroll
            for (int s = 0; s < DST; ++s) { dAv[s] = a; a *= r; }
        } else {
            #pragma unroll
            for (int s = 0; s < DST; ++s) dAv[s] = __expf(dtv * Ad[s]);
        }
        float yv = 0.f;
        #pragma unroll
        for (int s = 0; s < DST; ++s) {
            h[s] = fmaf(h[s], dAv[s], dtx * bc[64 + s]);
            yv = fmaf(h[s], bc[80 + s], yv);
        }
        float zv = bf2f(xz[m * (2 * DI) + DI + d]);
        ycat[m * (2 * DI) + (size_t)dirv * DI + d] =
            __float2bfloat16((yv + xv * Dsk) * siluf(zv));
    }
}

// fallback monolithic scan (both dirs) if ws too small for chunk bufs
__global__ __launch_bounds__(256) void scan_mono_k(
    const __hip_bfloat16* __restrict__ dtf2, const __hip_bfloat16* __restrict__ xsb2,
    const float* __restrict__ xdb2, const __hip_bfloat16* __restrict__ xz2,
    const float* __restrict__ fA, const float* __restrict__ bA,
    const float* __restrict__ fD, const float* __restrict__ bD,
    __hip_bfloat16* __restrict__ ycat)
{
    int d  = blockIdx.x * 256 + threadIdx.x;
    int bb = blockIdx.y;
    int dirv = blockIdx.z;
    const float* A_log = dirv ? bA : fA;
    const float* Dskip = dirv ? bD : fD;
    const __hip_bfloat16* dtf = dtf2 + (size_t)dirv * MR * DI;
    const __hip_bfloat16* xs = xsb2 + (size_t)dirv * MR * DI;
    const float* xdb = xdb2 + (size_t)dirv * MR * XLD;
    const __hip_bfloat16* xz = xz2 + (size_t)dirv * MR * 2 * DI;
    float Ad[DST], h[DST];
    #pragma unroll
    for (int s = 0; s < DST; ++s) { Ad[s] = -__expf(A_log[d * DST + s]); h[s] = 0.f; }
    float Dsk = Dskip[d];
    for (int i = 0; i < LL; ++i) {
        int t = dirv ? (LL - 1 - i) : i;
        size_t m = (size_t)bb * LL + t;
        float dtv = bf2f(dtf[m * DI + d]);
        float xv  = bf2f(xs[m * DI + d]);
        const float* bc = xdb + m * XLD;
        float dtx = dtv * xv;
        float yv = 0.f;
        #pragma unroll
        for (int s = 0; s < DST; ++s) {
            float dA = __expf(dtv * Ad[s]);
            h[s] = fmaf(h[s], dA, dtx * bc[64 + s]);
            yv = fmaf(h[s], bc[80 + s], yv);
        }
        float zv = bf2f(xz[m * (2 * DI) + DI + d]);
        ycat[m * (2 * DI) + (size_t)dirv * DI + d] =
            __float2bfloat16((yv + xv * Dsk) * siluf(zv));
    }
}

// ---------------- Launch ----------------
extern "C" void kernel_launch(void* const* d_in, const int* in_sizes, int n_in,
                              void* d_out, int out_size, void* d_ws, size_t ws_size,
                              hipStream_t stream)
{
    const float* x      = (const float*)d_in[0];
    const float* ln_w   = (const float*)d_in[1];
    const float* ln_b   = (const float*)d_in[2];
    const float* f_inW    = (const float*)d_in[3];
    const float* f_convW  = (const float*)d_in[4];
    const float* f_convb  = (const float*)d_in[5];
    const float* f_xprojW = (const float*)d_in[6];
    const float* f_dtW    = (const float*)d_in[7];
    const float* f_dtb    = (const float*)d_in[8];
    const float* f_A_log  = (const float*)d_in[9];
    const float* f_Dskip  = (const float*)d_in[10];
    const float* f_outW   = (const float*)d_in[11];
    const float* b_inW    = (const float*)d_in[12];
    const float* b_convW  = (const float*)d_in[13];
    const float* b_convb  = (const float*)d_in[14];
    const float* b_xprojW = (const float*)d_in[15];
    const float* b_dtW    = (const float*)d_in[16];
    const float* b_dtb    = (const float*)d_in[17];
    const float* b_A_log  = (const float*)d_in[18];
    const float* b_Dskip  = (const float*)d_in[19];
    const float* b_outW   = (const float*)d_in[20];
    const float* proj_W = (const float*)d_in[21];
    const float* proj_b = (const float*)d_in[22];

    float* ws = (float*)d_ws;
    size_t o = 0;
    __hip_bfloat16* xz2  = (__hip_bfloat16*)(ws + o);
    o += (size_t)2 * MR * 2 * DI / 2;
    __hip_bfloat16* xsb2 = (__hip_bfloat16*)(ws + o); o += (size_t)2 * MR * DI / 2;
    __hip_bfloat16* ycat = (__hip_bfloat16*)(ws + o);
    float* xpart = ws + o;
    o += (size_t)MR * 2 * DI / 2;
    float* xdb2 = ws + o; o += (size_t)2 * MR * XLD;
    __hip_bfloat16* xdbt = (__hip_bfloat16*)(ws + o); o += (size_t)2 * MR * 64 / 2;
    __hip_bfloat16* dtfb = (__hip_bfloat16*)(ws + o); o += (size_t)2 * MR * DI / 2;
    __hip_bfloat16* nb = (__hip_bfloat16*)(ws + o); o += (size_t)MR * DM / 2;
    __hip_bfloat16* warena = (__hip_bfloat16*)(ws + o); o += 15466496 / 2;
    float* hbuf = ws + o;
    size_t base_floats = o;

    __hip_bfloat16* wbi  = warena;               // [2][2DI][DM]    8,388,608
    __hip_bfloat16* pwb  = warena +  8388608;    // [DM][2DM]       2,097,152
    __hip_bfloat16* wdt  = warena + 10485760;    // [2][DI][64]       262,144
    __hip_bfloat16* wpb2 = warena + 10747904;    // [2][128][DI]      524,288
    __hip_bfloat16* wcat = warena + 11272192;    // [DM][2DI]       4,194,304

    const size_t slab = (size_t)NB * DI * DST;   // 65536
    int G = 32;
    while (G > 4 && (base_floats + 4ull * G * slab) * 4 > ws_size) G >>= 1;
    int useChunks = ((base_floats + 4ull * G * slab) * 4 <= ws_size);
    float* hend  = hbuf;
    float* aprod = hbuf + 2ull * G * slab;
    int Cn = useChunks ? LL / G : LL;

    // wot [2][DI][DM] bf16: in hbuf when chunked; else aliases xz2 (Wcat first).
    int wotInHbuf = useChunks && (4ull * G * slab >= 2097152ull);
    __hip_bfloat16* wot = wotInHbuf ? (__hip_bfloat16*)hbuf : xz2;

    // 1: mega-prep (weight cvts + transpose + layernorm)
    prep_k<<<5824, 256, 0, stream>>>(
        f_inW, b_inW, proj_W, f_dtW, b_dtW, warena,
        f_xprojW, b_xprojW, wpb2,
        f_outW, b_outW, wot,
        x, ln_w, ln_b, nb);

    // 2-3: in-proj, then merged conv+wcat (independent work, one dispatch)
    if (wotInHbuf) {
        inproj256_k<<<256, 512, 0, stream>>>(nb, wbi, xz2);
        conv_wcat_k<<<1280, 256, 0, stream>>>(
            xz2, f_convW, f_convb, b_convW, b_convb, xsb2, pwb, wot, wcat);
    } else {
        gemm_gl<1><<<dim3(DI / 128, DM / 128, 2), 256, 0, stream>>>(
            pwb, 2 * DM, (size_t)DM, wot, DM, (size_t)DI * DM,
            wcat, 2 * DI, (size_t)DI, DM, nullptr, nullptr);
        inproj256_k<<<256, 512, 0, stream>>>(nb, wbi, xz2);
        conv_silu_k<<<dim3(MR / 4, 2), 256, 0, stream>>>(
            xz2, f_convW, f_convb, b_convW, b_convb, xsb2);
    }

    // 4-5: x-proj split-K + reduce
    xproj_part_k<<<dim3(KS, MR / 128, 2), 256, 0, stream>>>(xsb2, wpb2, xpart);
    xproj_reduce_k<<<dim3((MR * XLD) / 1024, 2), 256, 0, stream>>>(xpart, xdb2, xdbt);

    // 6: dt-proj both dirs: dtfb = softplus(xdbt @ dtW^T + dtb) (bf16)
    gemm_gl<3><<<dim3(DI / 128, MR / 128, 2), 256, 0, stream>>>(
        xdbt, 64, (size_t)MR * 64, wdt, 64, (size_t)DI * 64,
        dtfb, DI, (size_t)MR * DI, 64, f_dtb, b_dtb);

    // 7-9: selective scan both dirs -> ycat [MR][2*DI]  (3-dispatch, proven)
    if (useChunks) {
        scan1_k<<<dim3(DI / 256, NB, 2 * G), 256, 0, stream>>>(
            dtfb, xsb2, xdb2, f_A_log, b_A_log, hend, aprod, G, Cn);
        scan2_k<<<dim3((NB * DI * DST) / 256, 2), 256, 0, stream>>>(hend, aprod, G);
        scan3_k<<<dim3(DI / 256, NB, 2 * G), 256, 0, stream>>>(
            dtfb, xsb2, xdb2, xz2, f_A_log, b_A_log, f_Dskip, b_Dskip,
            hend, ycat, G, Cn);
    } else {
        scan_mono_k<<<dim3(DI / 256, NB, 2), 256, 0, stream>>>(
            dtfb, xsb2, xdb2, xz2, f_A_log, b_A_log, f_Dskip, b_Dskip, ycat);
    }

    // 10: fused out-proj: out = x + proj_b + ycat @ wcat^T
    outproj_k<<<dim3(DM / 64, MR / 64), 256, 0, stream>>>(
        ycat, wcat, x, proj_b, (float*)d_out);
}

// Round 12
// 374.945 us; speedup vs baseline: 1.0783x; 1.0316x over previous
//
#include <hip/hip_runtime.h>
#include <hip/hip_bf16.h>
#include <math.h>

#define DM   1024   // d_model
#define DI   2048   // d_inner
#define DTR  64     // dt_rank
#define DST  16     // d_state
#define NB   2      // batch
#define LL   1024   // seq len
#define MR   (NB*LL)  // 2048 rows
#define XLD  128    // xdb padded leading dim
#define KS   8      // split-K factor for x-proj

typedef __bf16 bf16x8 __attribute__((ext_vector_type(8)));
typedef float  f32x4  __attribute__((ext_vector_type(4)));
typedef unsigned short u16x8 __attribute__((ext_vector_type(8)));

__device__ __forceinline__ float siluf(float x) { return x / (1.f + __expf(-x)); }
__device__ __forceinline__ float softplusf(float x) {
    return fmaxf(x, 0.f) + log1pf(__expf(-fabsf(x)));
}
__device__ __forceinline__ unsigned short f2bf(float f) {
    __hip_bfloat16 h = __float2bfloat16(f);
    return *reinterpret_cast<unsigned short*>(&h);
}
__device__ __forceinline__ float bf2f(__hip_bfloat16 h) { return __bfloat162float(h); }
__device__ __forceinline__ float bfu2f(unsigned short u) {
    __hip_bfloat16 h = *reinterpret_cast<__hip_bfloat16*>(&u);
    return __bfloat162float(h);
}

__device__ __forceinline__ void gl2lds16(const __hip_bfloat16* g, __hip_bfloat16* l)
{
    __builtin_amdgcn_global_load_lds(
        (const __attribute__((address_space(1))) unsigned int*)g,
        (__attribute__((address_space(3))) unsigned int*)l, 16, 0, 0);
}

// ---------------- mega-prep: weight cvts + transpose + layernorm ----------------
__global__ __launch_bounds__(256) void prep_k(
    const float* __restrict__ s0, const float* __restrict__ s1,
    const float* __restrict__ s2, const float* __restrict__ s3,
    const float* __restrict__ s4, __hip_bfloat16* __restrict__ warena,
    const float* __restrict__ fx, const float* __restrict__ bx,
    __hip_bfloat16* __restrict__ wpb2,
    const float* __restrict__ fo, const float* __restrict__ bo,
    __hip_bfloat16* __restrict__ wot,
    const float* __restrict__ x, const float* __restrict__ lnw,
    const float* __restrict__ lnb, __hip_bfloat16* __restrict__ nb)
{
    __shared__ float pshm[64 * 65];
    const int b = blockIdx.x;
    const int tid = threadIdx.x;

    if (b < 2624) {
        long base = (long)b * 4096;
        const float* src; long off;
        if      (base <  4194304L) { src = s0; off = base; }
        else if (base <  8388608L) { src = s1; off = base -  4194304L; }
        else if (base < 10485760L) { src = s2; off = base -  8388608L; }
        else if (base < 10616832L) { src = s3; off = base - 10485760L; }
        else                       { src = s4; off = base - 10616832L; }
        #pragma unroll
        for (int j = 0; j < 4; ++j) {
            long e = (long)j * 1024 + tid * 4;
            float4 v = *(const float4*)(src + off + e);
            ushort4 o;
            o.x = f2bf(v.x); o.y = f2bf(v.y); o.z = f2bf(v.z); o.w = f2bf(v.w);
            *(ushort4*)((unsigned short*)warena + base + e) = o;
        }
    } else if (b < 2752) {
        int t = b - 2624;
        int z = t >> 6;
        const float* in = z ? bx : fx;
        int idx = ((t & 63) * 256 + tid) * 4;   // over 128*DI
        int row = idx >> 11;
        ushort4 o = make_ushort4(0, 0, 0, 0);
        if (row < 96) {
            float4 v = *(const float4*)(in + idx);
            o.x = f2bf(v.x); o.y = f2bf(v.y); o.z = f2bf(v.z); o.w = f2bf(v.w);
        }
        *(ushort4*)((unsigned short*)wpb2 + (size_t)z * 128 * DI + idx) = o;
    } else if (b < 3776) {
        int t = b - 2752;
        int z = t >> 9; t &= 511;
        const float* src = z ? bo : fo;
        int c0 = (t & 31) * 64;    // col in src (DI dim)
        int r0 = (t >> 5) * 64;    // row in src (DM dim)
        int tc = tid & 63;
        int tr = tid >> 6;
        #pragma unroll
        for (int ii = 0; ii < 16; ++ii) {
            int rl = tr + ii * 4;
            pshm[tc * 65 + rl] = src[(size_t)(r0 + rl) * DI + c0 + tc];
        }
        __syncthreads();
        __hip_bfloat16* dst = wot + (size_t)z * DI * DM;
        #pragma unroll
        for (int ii = 0; ii < 16; ++ii) {
            int cl = tr + ii * 4;
            dst[(size_t)(c0 + cl) * DM + r0 + tc] = __float2bfloat16(pshm[cl * 65 + tc]);
        }
    } else {
        int row = b - 3776;
        const float* xr = x + (size_t)row * DM;
        float4 v = *(const float4*)(xr + tid * 4);
        float s = v.x + v.y + v.z + v.w;
        float q = v.x*v.x + v.y*v.y + v.z*v.z + v.w*v.w;
        #pragma unroll
        for (int off = 32; off > 0; off >>= 1) {
            s += __shfl_xor(s, off, 64);
            q += __shfl_xor(q, off, 64);
        }
        int wv = tid >> 6;
        if ((tid & 63) == 0) { pshm[wv] = s; pshm[8 + wv] = q; }
        __syncthreads();
        s = pshm[0] + pshm[1] + pshm[2] + pshm[3];
        q = pshm[8] + pshm[9] + pshm[10] + pshm[11];
        float mu  = s * (1.f / DM);
        float var = q * (1.f / DM) - mu * mu;
        float rstd = rsqrtf(var + 1e-5f);
        float4 wv4 = *(const float4*)(lnw + tid * 4);
        float4 bv4 = *(const float4*)(lnb + tid * 4);
        ushort4 o;
        o.x = f2bf((v.x - mu) * rstd * wv4.x + bv4.x);
        o.y = f2bf((v.y - mu) * rstd * wv4.y + bv4.y);
        o.z = f2bf((v.z - mu) * rstd * wv4.z + bv4.z);
        o.w = f2bf((v.w - mu) * rstd * wv4.w + bv4.w);
        *(ushort4*)((unsigned short*)nb + (size_t)row * DM + tid * 4) = o;
    }
}

// ---------------- in-proj: 256x128 tile, BK=64, single-buffer, 2 blocks/CU ----------------
// C[z] = nb[2048x1024] @ inW[z]^T[4096x1024] -> xz2[z][2048][4096] bf16.
// 512 threads = 8 waves (4M x 2N); per-wave C = 64x64 (4x4 frags, acc 64 f32).
// LDS 48 KiB (As[256][64] + Bs[128][64]) -> 2 blocks/CU co-resident; the
// barrier/vmcnt drain of one block overlaps the other block's MFMA (m114
// inter-block wave overlap) — no intra-block pipelining needed (m97 pattern).
// Staging invariant (proven in gemm_gl): LDS[row][sp] holds global col-seg
// (sp ^ (row&7)); stage cg = ((tid&7)^((tid>>3)&7))*8, read pc =
// ((kk*4+quad)^(fr&7))*8 with row&7 == fr&7 for all frag rows.
__global__ __launch_bounds__(512) void inproj256_k(
    const __hip_bfloat16* __restrict__ A,
    const __hip_bfloat16* __restrict__ Bmat,
    __hip_bfloat16* __restrict__ C)
{
    __shared__ __hip_bfloat16 smem[24576];   // 48 KiB
    __hip_bfloat16* const As = smem;          // [256][64]
    __hip_bfloat16* const Bs = smem + 16384;  // [128][64]
    const int tid = threadIdx.x;
    // XCD swizzle: 512 blocks = 8 XCDs x 64 contiguous tiles.
    int id = blockIdx.x;
    int s  = (id & 7) * 64 + (id >> 3);
    const int z  = s >> 8;
    const int r  = s & 255;
    const int bm = (r & 7) * 256;     // 8 M-tiles
    const int bn = (r >> 3) * 128;    // 32 N-tiles
    const __hip_bfloat16* Az = A;
    const __hip_bfloat16* Bz = Bmat + (size_t)z * 2 * DI * DM;
    __hip_bfloat16* Cz = C + (size_t)z * MR * 2 * DI;

    const int wv   = tid >> 6;
    const int lane = tid & 63;
    const int wm   = wv >> 1;      // 0..3 (64-row strip)
    const int wn   = wv & 1;       // 0..1 (64-col strip)
    const int fr   = lane & 15;
    const int quad = lane >> 4;
    const int sr8  = tid >> 3;     // 0..63
    const int cg   = ((tid & 7) ^ (sr8 & 7)) * 8;

    f32x4 acc[4][4] = {};

    for (int k0 = 0; k0 < DM; k0 += 64) {
        __syncthreads();
        #pragma unroll
        for (int i = 0; i < 4; ++i)
            gl2lds16(Az + (size_t)(bm + sr8 + i * 64) * DM + k0 + cg,
                     As + i * 4096 + tid * 8);
        #pragma unroll
        for (int i = 0; i < 2; ++i)
            gl2lds16(Bz + (size_t)(bn + sr8 + i * 64) * DM + k0 + cg,
                     Bs + i * 4096 + tid * 8);
        __syncthreads();
        #pragma unroll
        for (int kk = 0; kk < 2; ++kk) {
            const int pc = ((kk * 4 + quad) ^ (fr & 7)) * 8;
            bf16x8 af[4], bf_[4];
            #pragma unroll
            for (int i = 0; i < 4; ++i)
                af[i]  = *(const bf16x8*)(As + (wm * 64 + i * 16 + fr) * 64 + pc);
            #pragma unroll
            for (int j = 0; j < 4; ++j)
                bf_[j] = *(const bf16x8*)(Bs + (wn * 64 + j * 16 + fr) * 64 + pc);
            __builtin_amdgcn_s_setprio(1);
            #pragma unroll
            for (int i = 0; i < 4; ++i)
                #pragma unroll
                for (int j = 0; j < 4; ++j)
                    acc[i][j] = __builtin_amdgcn_mfma_f32_16x16x32_bf16(
                        af[i], bf_[j], acc[i][j], 0, 0, 0);
            __builtin_amdgcn_s_setprio(0);
        }
    }

    // epilogue: 4 passes of 64 rows via LDS restage (eps[64][132]) -> 32 B/thread
    float* eps = (float*)smem;
    const int orow = tid >> 3;          // 0..63
    const int ocol = (tid & 7) * 16;    // 0..112
    #pragma unroll
    for (int p = 0; p < 4; ++p) {
        __syncthreads();
        if (wm == p) {
            #pragma unroll
            for (int i = 0; i < 4; ++i)
                #pragma unroll
                for (int j = 0; j < 4; ++j)
                    #pragma unroll
                    for (int rr = 0; rr < 4; ++rr)
                        eps[(i * 16 + quad * 4 + rr) * 132 + wn * 64 + j * 16 + fr]
                            = acc[i][j][rr];
        }
        __syncthreads();
        float vals[16];
        *(float4*)(vals +  0) = *(const float4*)(eps + orow * 132 + ocol +  0);
        *(float4*)(vals +  4) = *(const float4*)(eps + orow * 132 + ocol +  4);
        *(float4*)(vals +  8) = *(const float4*)(eps + orow * 132 + ocol +  8);
        *(float4*)(vals + 12) = *(const float4*)(eps + orow * 132 + ocol + 12);
        unsigned short os[16] __attribute__((aligned(16)));
        #pragma unroll
        for (int c = 0; c < 16; ++c) os[c] = f2bf(vals[c]);
        unsigned short* dst = (unsigned short*)Cz +
            (size_t)(bm + p * 64 + orow) * (2 * DI) + bn + ocol;
        *(ushort4*)(dst +  0) = *(ushort4*)(os +  0);
        *(ushort4*)(dst +  4) = *(ushort4*)(os +  4);
        *(ushort4*)(dst +  8) = *(ushort4*)(os +  8);
        *(ushort4*)(dst + 12) = *(ushort4*)(os + 12);
    }
}

// ---------------- bf16 MFMA GEMM with global_load_lds staging ----------------
// EPI: 1 = bf16 store, 3 = softplus(v+bias_z[n]) bf16 store.
template<int EPI>
__global__ __launch_bounds__(256) void gemm_gl(
    const __hip_bfloat16* __restrict__ A, int lda, size_t aofs,
    const __hip_bfloat16* __restrict__ B, int ldb, size_t bofs,
    void* __restrict__ Cp, int ldc, size_t cofs, int K,
    const float* __restrict__ bias0, const float* __restrict__ bias1)
{
    __shared__ __hip_bfloat16 smem[2 * 128 * 64];
    __hip_bfloat16* As = smem;
    __hip_bfloat16* Bs = smem + 128 * 64;
    const int tid  = threadIdx.x;
    const int z    = blockIdx.z;
    const int bm   = blockIdx.y * 128;
    const int bn   = blockIdx.x * 128;
    const __hip_bfloat16* Az = A + (size_t)z * aofs;
    const __hip_bfloat16* Bz = B + (size_t)z * bofs;
    const int wv   = tid >> 6;
    const int lane = tid & 63;
    const int wr   = (wv >> 1) * 64;
    const int wc   = (wv & 1) * 64;
    const int srow = wv * 32 + (lane >> 3);
    const int cg   = ((lane & 7) ^ (lane >> 3)) * 8;
    const int fr   = lane & 15;
    const int quad = lane >> 4;
    const int pc0  = (quad ^ (fr & 7)) * 8;
    const int pc1  = ((4 + quad) ^ (fr & 7)) * 8;

    f32x4 acc[4][4] = {};

    for (int k0 = 0; k0 < K; k0 += 64) {
        __syncthreads();
        #pragma unroll
        for (int i = 0; i < 4; ++i) {
            int r = srow + i * 8;
            gl2lds16(Az + (size_t)(bm + r) * lda + k0 + cg, As + wv * 2048 + i * 512);
            gl2lds16(Bz + (size_t)(bn + r) * ldb + k0 + cg, Bs + wv * 2048 + i * 512);
        }
        __syncthreads();
        #pragma unroll
        for (int kk = 0; kk < 2; ++kk) {
            const int pc = kk ? pc1 : pc0;
            bf16x8 af[4], bf_[4];
            #pragma unroll
            for (int i = 0; i < 4; ++i) {
                af[i]  = *(const bf16x8*)(As + (wr + i * 16 + fr) * 64 + pc);
                bf_[i] = *(const bf16x8*)(Bs + (wc + i * 16 + fr) * 64 + pc);
            }
            #pragma unroll
            for (int i = 0; i < 4; ++i)
                #pragma unroll
                for (int j = 0; j < 4; ++j)
                    acc[i][j] = __builtin_amdgcn_mfma_f32_16x16x32_bf16(
                        af[i], bf_[j], acc[i][j], 0, 0, 0);
        }
    }

    const float* bias = (EPI == 3) ? (z ? bias1 : bias0) : nullptr;
    float* eps = (float*)smem;
    const int half = wv >> 1;
    const int lrow = tid >> 3;
    const int cseg = (tid & 7) * 16;
    const int gr_  = bm + (lrow >> 4) * 64 + (lrow & 15);
    #pragma unroll
    for (int i = 0; i < 4; ++i) {
        __syncthreads();
        #pragma unroll
        for (int j = 0; j < 4; ++j)
            #pragma unroll
            for (int r = 0; r < 4; ++r)
                eps[(half * 16 + quad * 4 + r) * 132 + wc + j * 16 + fr] = acc[i][j][r];
        __syncthreads();
        float vals[16];
        *(float4*)(vals +  0) = *(const float4*)(eps + lrow * 132 + cseg +  0);
        *(float4*)(vals +  4) = *(const float4*)(eps + lrow * 132 + cseg +  4);
        *(float4*)(vals +  8) = *(const float4*)(eps + lrow * 132 + cseg +  8);
        *(float4*)(vals + 12) = *(const float4*)(eps + lrow * 132 + cseg + 12);
        int gr = gr_ + i * 16;
        int gc = bn + cseg;
        unsigned short os[16];
        #pragma unroll
        for (int c = 0; c < 16; ++c) {
            float t = vals[c];
            if (EPI == 3) t = softplusf(t + bias[gc + c]);
            os[c] = f2bf(t);
        }
        unsigned short* dst = (unsigned short*)Cp + (size_t)z * cofs +
                              (size_t)gr * ldc + gc;
        *(ushort4*)(dst +  0) = *(ushort4*)(os +  0);
        *(ushort4*)(dst +  4) = *(ushort4*)(os +  4);
        *(ushort4*)(dst +  8) = *(ushort4*)(os +  8);
        *(ushort4*)(dst + 12) = *(ushort4*)(os + 12);
    }
}

// ---------------- merged conv+silu (blocks 0..1023) + Wcat gemm (1024..1279) ----------------
__global__ __launch_bounds__(256) void conv_wcat_k(
    const __hip_bfloat16* __restrict__ xz2,
    const float* __restrict__ fW, const float* __restrict__ fb,
    const float* __restrict__ bW, const float* __restrict__ bb_,
    __hip_bfloat16* __restrict__ xsb2,
    const __hip_bfloat16* __restrict__ pwb,
    const __hip_bfloat16* __restrict__ wot,
    __hip_bfloat16* __restrict__ wcat)
{
    __shared__ __hip_bfloat16 smem[2 * 128 * 64];
    const int b   = blockIdx.x;
    const int tid = threadIdx.x;

    if (b < 1024) {
        // ---- conv branch ----
        const int dirv  = b >> 9;
        const int chunk = b & 511;
        const int bb    = chunk >> 8;
        const int t0    = (chunk & 255) * 4;
        const int d     = tid * 8;

        const float* w    = (dirv ? bW : fW) + d * 4;
        const float* bias = (dirv ? bb_ : fb) + d;
        const unsigned short* xz =
            (const unsigned short*)(xz2 + (size_t)dirv * MR * 2 * DI) + d;

        u16x8 rows[7];
        #pragma unroll
        for (int rr = 0; rr < 7; ++rr) {
            int t = dirv ? (t0 + rr) : (t0 - 3 + rr);
            bool ok = dirv ? (t < LL) : (t >= 0);
            u16x8 v = {};
            if (ok) v = *(const u16x8*)(xz + (size_t)(bb * LL + t) * (2 * DI));
            rows[rr] = v;
        }
        float wq[8][4];
        #pragma unroll
        for (int c = 0; c < 8; ++c) {
            float4 t = *(const float4*)(w + c * 4);
            if (dirv) { wq[c][0]=t.w; wq[c][1]=t.z; wq[c][2]=t.y; wq[c][3]=t.x; }
            else      { wq[c][0]=t.x; wq[c][1]=t.y; wq[c][2]=t.z; wq[c][3]=t.w; }
        }
        float4 b0 = *(const float4*)(bias);
        float4 b1 = *(const float4*)(bias + 4);
        float bs[8] = {b0.x, b0.y, b0.z, b0.w, b1.x, b1.y, b1.z, b1.w};

        unsigned short* outp = (unsigned short*)xsb2 + (size_t)dirv * MR * DI +
                               (size_t)(bb * LL + t0) * DI + d;
        #pragma unroll
        for (int o = 0; o < 4; ++o) {
            unsigned short os[8] __attribute__((aligned(16)));
            #pragma unroll
            for (int c = 0; c < 8; ++c) {
                float a = bs[c];
                #pragma unroll
                for (int k = 0; k < 4; ++k)
                    a = fmaf(wq[c][k], bfu2f(rows[o + k][c]), a);
                os[c] = f2bf(siluf(a));
            }
            *(uint4*)(outp + (size_t)o * DI) = *(const uint4*)os;
        }
        return;
    }

    // ---- wcat branch: gemm body, lda=2*DM, ldb=DM, ldc=2*DI, K=DM ----
    const int t_   = b - 1024;
    const int bn   = (t_ & 15) * 128;         // over DI cols
    const int bm   = ((t_ >> 4) & 7) * 128;   // over DM rows
    const int z    = t_ >> 7;                 // dir
    const __hip_bfloat16* Az = pwb + (size_t)z * DM;
    const __hip_bfloat16* Bz = wot + (size_t)z * DI * DM;
    __hip_bfloat16* As = smem;
    __hip_bfloat16* Bs = smem + 128 * 64;
    const int wv   = tid >> 6;
    const int lane = tid & 63;
    const int wr   = (wv >> 1) * 64;
    const int wc   = (wv & 1) * 64;
    const int srow = wv * 32 + (lane >> 3);
    const int cg   = ((lane & 7) ^ (lane >> 3)) * 8;
    const int fr   = lane & 15;
    const int quad = lane >> 4;
    const int pc0  = (quad ^ (fr & 7)) * 8;
    const int pc1  = ((4 + quad) ^ (fr & 7)) * 8;

    f32x4 acc[4][4] = {};

    for (int k0 = 0; k0 < DM; k0 += 64) {
        __syncthreads();
        #pragma unroll
        for (int i = 0; i < 4; ++i) {
            int r = srow + i * 8;
            gl2lds16(Az + (size_t)(bm + r) * (2 * DM) + k0 + cg, As + wv * 2048 + i * 512);
            gl2lds16(Bz + (size_t)(bn + r) * DM + k0 + cg,       Bs + wv * 2048 + i * 512);
        }
        __syncthreads();
        #pragma unroll
        for (int kk = 0; kk < 2; ++kk) {
            const int pc = kk ? pc1 : pc0;
            bf16x8 af[4], bf_[4];
            #pragma unroll
            for (int i = 0; i < 4; ++i) {
                af[i]  = *(const bf16x8*)(As + (wr + i * 16 + fr) * 64 + pc);
                bf_[i] = *(const bf16x8*)(Bs + (wc + i * 16 + fr) * 64 + pc);
            }
            #pragma unroll
            for (int i = 0; i < 4; ++i)
                #pragma unroll
                for (int j = 0; j < 4; ++j)
                    acc[i][j] = __builtin_amdgcn_mfma_f32_16x16x32_bf16(
                        af[i], bf_[j], acc[i][j], 0, 0, 0);
        }
    }

    float* eps = (float*)smem;
    const int half = wv >> 1;
    const int lrow = tid >> 3;
    const int cseg = (tid & 7) * 16;
    const int gr_  = bm + (lrow >> 4) * 64 + (lrow & 15);
    #pragma unroll
    for (int i = 0; i < 4; ++i) {
        __syncthreads();
        #pragma unroll
        for (int j = 0; j < 4; ++j)
            #pragma unroll
            for (int r = 0; r < 4; ++r)
                eps[(half * 16 + quad * 4 + r) * 132 + wc + j * 16 + fr] = acc[i][j][r];
        __syncthreads();
        float vals[16];
        *(float4*)(vals +  0) = *(const float4*)(eps + lrow * 132 + cseg +  0);
        *(float4*)(vals +  4) = *(const float4*)(eps + lrow * 132 + cseg +  4);
        *(float4*)(vals +  8) = *(const float4*)(eps + lrow * 132 + cseg +  8);
        *(float4*)(vals + 12) = *(const float4*)(eps + lrow * 132 + cseg + 12);
        int gr = gr_ + i * 16;
        int gc = bn + cseg;
        unsigned short os[16];
        #pragma unroll
        for (int c = 0; c < 16; ++c) os[c] = f2bf(vals[c]);
        unsigned short* dst = (unsigned short*)wcat + (size_t)z * DI +
                              (size_t)gr * (2 * DI) + gc;
        *(ushort4*)(dst +  0) = *(ushort4*)(os +  0);
        *(ushort4*)(dst +  4) = *(ushort4*)(os +  4);
        *(ushort4*)(dst +  8) = *(ushort4*)(os +  8);
        *(ushort4*)(dst + 12) = *(ushort4*)(os + 12);
    }
}

// ---------------- fused out-proj: out = x + proj_b + ycat @ wcat^T ----------------
__global__ __launch_bounds__(256) void outproj_k(
    const __hip_bfloat16* __restrict__ A,   // ycat [MR][4096]
    const __hip_bfloat16* __restrict__ Bm,  // wcat [DM][4096]
    const float* __restrict__ x, const float* __restrict__ proj_b,
    float* __restrict__ out)
{
    __shared__ __hip_bfloat16 smem[2 * 64 * 64];
    __hip_bfloat16* As = smem;
    __hip_bfloat16* Bs = smem + 64 * 64;
    const int tid  = threadIdx.x;
    const int bn   = blockIdx.x * 64;
    const int bm   = blockIdx.y * 64;
    const int wv   = tid >> 6;
    const int lane = tid & 63;
    const int wr   = (wv >> 1) * 32;
    const int wc   = (wv & 1) * 32;
    const int srow = wv * 16 + (lane >> 3);
    const int cg   = ((lane & 7) ^ (lane >> 3)) * 8;
    const int fr   = lane & 15;
    const int quad = lane >> 4;
    const int pc0  = (quad ^ (fr & 7)) * 8;
    const int pc1  = ((4 + quad) ^ (fr & 7)) * 8;
    const int K    = 2 * DI;

    f32x4 acc[2][2] = {};

    for (int k0 = 0; k0 < K; k0 += 64) {
        __syncthreads();
        #pragma unroll
        for (int j = 0; j < 2; ++j) {
            int r = srow + j * 8;
            gl2lds16(A  + (size_t)(bm + r) * K + k0 + cg, As + wv * 1024 + j * 512);
            gl2lds16(Bm + (size_t)(bn + r) * K + k0 + cg, Bs + wv * 1024 + j * 512);
        }
        __syncthreads();
        #pragma unroll
        for (int kk = 0; kk < 2; ++kk) {
            const int pc = kk ? pc1 : pc0;
            bf16x8 af[2], bf_[2];
            #pragma unroll
            for (int i = 0; i < 2; ++i) {
                af[i]  = *(const bf16x8*)(As + (wr + i * 16 + fr) * 64 + pc);
                bf_[i] = *(const bf16x8*)(Bs + (wc + i * 16 + fr) * 64 + pc);
            }
            #pragma unroll
            for (int i = 0; i < 2; ++i)
                #pragma unroll
                for (int j = 0; j < 2; ++j)
                    acc[i][j] = __builtin_amdgcn_mfma_f32_16x16x32_bf16(
                        af[i], bf_[j], acc[i][j], 0, 0, 0);
        }
    }

    const float pb0 = proj_b[bn + wc + fr];
    const float pb1 = proj_b[bn + wc + 16 + fr];
    #pragma unroll
    for (int i = 0; i < 2; ++i)
        #pragma unroll
        for (int j = 0; j < 2; ++j) {
            const int gc = bn + wc + j * 16 + fr;
            const float pb = j ? pb1 : pb0;
            #pragma unroll
            for (int r = 0; r < 4; ++r) {
                size_t off = (size_t)(bm + wr + i * 16 + quad * 4 + r) * DM + gc;
                out[off] = x[off] + pb + acc[i][j][r];
            }
        }
}

// ---------------- x-proj split-K partials, grouped over dir ----------------
__global__ __launch_bounds__(256) void xproj_part_k(
    const __hip_bfloat16* __restrict__ A,
    const __hip_bfloat16* __restrict__ B,
    float* __restrict__ part)
{
    __shared__ __hip_bfloat16 smem[2 * 128 * 64];
    __hip_bfloat16* As = smem;
    __hip_bfloat16* Bs = smem + 128 * 64;
    const int tid  = threadIdx.x;
    const int ks   = blockIdx.x;
    const int bm   = blockIdx.y * 128;
    const int z    = blockIdx.z;
    const __hip_bfloat16* Az = A + (size_t)z * MR * DI;
    const __hip_bfloat16* Bz = B + (size_t)z * 128 * DI;
    const int kb   = ks * (DI / KS);
    const int wv   = tid >> 6;
    const int lane = tid & 63;
    const int wr   = (wv >> 1) * 64;
    const int wc   = (wv & 1) * 64;
    const int srow = wv * 32 + (lane >> 3);
    const int cg   = ((lane & 7) ^ (lane >> 3)) * 8;
    const int fr   = lane & 15;
    const int quad = lane >> 4;
    const int pc0  = (quad ^ (fr & 7)) * 8;
    const int pc1  = ((4 + quad) ^ (fr & 7)) * 8;

    f32x4 acc[4][4] = {};

    #pragma unroll
    for (int k0 = 0; k0 < DI / KS; k0 += 64) {
        __syncthreads();
        #pragma unroll
        for (int i = 0; i < 4; ++i) {
            int r = srow + i * 8;
            gl2lds16(Az + (size_t)(bm + r) * DI + kb + k0 + cg, As + wv * 2048 + i * 512);
            gl2lds16(Bz + (size_t)r * DI + kb + k0 + cg,        Bs + wv * 2048 + i * 512);
        }
        __syncthreads();
        #pragma unroll
        for (int kk = 0; kk < 2; ++kk) {
            const int pc = kk ? pc1 : pc0;
            bf16x8 af[4], bf_[4];
            #pragma unroll
            for (int i = 0; i < 4; ++i) {
                af[i]  = *(const bf16x8*)(As + (wr + i * 16 + fr) * 64 + pc);
                bf_[i] = *(const bf16x8*)(Bs + (wc + i * 16 + fr) * 64 + pc);
            }
            #pragma unroll
            for (int i = 0; i < 4; ++i)
                #pragma unroll
                for (int j = 0; j < 4; ++j)
                    acc[i][j] = __builtin_amdgcn_mfma_f32_16x16x32_bf16(
                        af[i], bf_[j], acc[i][j], 0, 0, 0);
        }
    }

    float* dst = part + ((size_t)z * KS + ks) * MR * XLD;
    const int er = quad * 4;
    #pragma unroll
    for (int i = 0; i < 4; ++i)
        #pragma unroll
        for (int j = 0; j < 4; ++j) {
            int row = bm + wr + i * 16 + er;
            int col = wc + j * 16 + fr;
            #pragma unroll
            for (int r = 0; r < 4; ++r)
                dst[(size_t)(row + r) * XLD + col] = acc[i][j][r];
        }
}

// ---------------- reduce x-proj partials -> xdb2 fp32 + dt-cols bf16 ----------------
__global__ __launch_bounds__(256) void xproj_reduce_k(
    const float* __restrict__ part, float* __restrict__ xdb,
    __hip_bfloat16* __restrict__ xdbt)
{
    int z = blockIdx.y;
    size_t idx = ((size_t)blockIdx.x * 256 + threadIdx.x) * 4;   // over MR*XLD
    const float* p = part + (size_t)z * KS * MR * XLD;
    float4 s = make_float4(0.f, 0.f, 0.f, 0.f);
    #pragma unroll
    for (int ks = 0; ks < KS; ++ks) {
        float4 v = *(const float4*)(p + (size_t)ks * MR * XLD + idx);
        s.x += v.x; s.y += v.y; s.z += v.z; s.w += v.w;
    }
    *(float4*)(xdb + (size_t)z * MR * XLD + idx) = s;
    int c = (int)(idx & (XLD - 1));
    if (c < 64) {
        size_t m = idx >> 7;
        ushort4 o;
        o.x = f2bf(s.x); o.y = f2bf(s.y); o.z = f2bf(s.z); o.w = f2bf(s.w);
        *(ushort4*)((unsigned short*)xdbt + (size_t)z * MR * 64 + m * 64 + c) = o;
    }
}

// ---------------- conv fallback (wotInHbuf==0 path) ----------------
__global__ __launch_bounds__(256) void conv_silu_k(
    const __hip_bfloat16* __restrict__ xz2,
    const float* __restrict__ fW, const float* __restrict__ fb,
    const float* __restrict__ bW, const float* __restrict__ bb_,
    __hip_bfloat16* __restrict__ xsb2)
{
    const int dirv  = blockIdx.y;
    const int chunk = blockIdx.x;
    const int bb    = chunk >> 8;
    const int t0    = (chunk & 255) * 4;
    const int d     = threadIdx.x * 8;

    const float* w    = (dirv ? bW : fW) + d * 4;
    const float* bias = (dirv ? bb_ : fb) + d;
    const unsigned short* xz =
        (const unsigned short*)(xz2 + (size_t)dirv * MR * 2 * DI) + d;

    u16x8 rows[7];
    #pragma unroll
    for (int rr = 0; rr < 7; ++rr) {
        int t = dirv ? (t0 + rr) : (t0 - 3 + rr);
        bool ok = dirv ? (t < LL) : (t >= 0);
        u16x8 v = {};
        if (ok) v = *(const u16x8*)(xz + (size_t)(bb * LL + t) * (2 * DI));
        rows[rr] = v;
    }
    float wq[8][4];
    #pragma unroll
    for (int c = 0; c < 8; ++c) {
        float4 t = *(const float4*)(w + c * 4);
        if (dirv) { wq[c][0]=t.w; wq[c][1]=t.z; wq[c][2]=t.y; wq[c][3]=t.x; }
        else      { wq[c][0]=t.x; wq[c][1]=t.y; wq[c][2]=t.z; wq[c][3]=t.w; }
    }
    float4 b0 = *(const float4*)(bias);
    float4 b1 = *(const float4*)(bias + 4);
    float bs[8] = {b0.x, b0.y, b0.z, b0.w, b1.x, b1.y, b1.z, b1.w};

    unsigned short* outp = (unsigned short*)xsb2 + (size_t)dirv * MR * DI +
                           (size_t)(bb * LL + t0) * DI + d;
    #pragma unroll
    for (int o = 0; o < 4; ++o) {
        unsigned short os[8] __attribute__((aligned(16)));
        #pragma unroll
        for (int c = 0; c < 8; ++c) {
            float a = bs[c];
            #pragma unroll
            for (int k = 0; k < 4; ++k)
                a = fmaf(wq[c][k], bfu2f(rows[o + k][c]), a);
            os[c] = f2bf(siluf(a));
        }
        *(uint4*)(outp + (size_t)o * DI) = *(const uint4*)os;
    }
}

// ---------------- Chunked selective scan, both dirs (3-dispatch, proven) ----------------
__global__ __launch_bounds__(256) void scan1_k(
    const __hip_bfloat16* __restrict__ dtf2, const __hip_bfloat16* __restrict__ xsb2,
    const float* __restrict__ xdb2,
    const float* __restrict__ fA, const float* __restrict__ bA,
    float* __restrict__ hend, float* __restrict__ aprod, int G, int Cn)
{
    int d  = blockIdx.x * 256 + threadIdx.x;
    int bb = blockIdx.y;
    int zz = blockIdx.z;
    int dirv = (zz >= G) ? 1 : 0;
    int g = zz - (dirv ? G : 0);
    const float* A_log = dirv ? bA : fA;
    const __hip_bfloat16* dtf = dtf2 + (size_t)dirv * MR * DI;
    const __hip_bfloat16* xs = xsb2 + (size_t)dirv * MR * DI;
    const float* xdb = xdb2 + (size_t)dirv * MR * XLD;
    size_t hoff = (size_t)dirv * G * (NB * DI * DST);

    float Ad[DST], h[DST], ap[DST];
    bool pw = true;
    #pragma unroll
    for (int s = 0; s < DST; ++s) {
        Ad[s] = -__expf(A_log[d * DST + s]);
        pw = pw && (fabsf(Ad[s] + (float)(s + 1)) < 1e-3f * (s + 1));
        h[s] = 0.f; ap[s] = 1.f;
    }
    int i0 = g * Cn;
    for (int i = 0; i < Cn; ++i) {
        int ii = i0 + i;
        int t = dirv ? (LL - 1 - ii) : ii;
        size_t m = (size_t)bb * LL + t;
        float dtv = bf2f(dtf[m * DI + d]);
        float xv  = bf2f(xs[m * DI + d]);
        const float* bc = xdb + m * XLD;
        float dtx = dtv * xv;
        float dAv[DST];
        if (pw) {
            float r = __expf(-dtv);
            float a = r;
            #pragma unroll
            for (int s = 0; s < DST; ++s) { dAv[s] = a; a *= r; }
        } else {
            #pragma unroll
            for (int s = 0; s < DST; ++s) dAv[s] = __expf(dtv * Ad[s]);
        }
        #pragma unroll
        for (int s = 0; s < DST; ++s) {
            h[s] = fmaf(h[s], dAv[s], dtx * bc[64 + s]);
            ap[s] *= dAv[s];
        }
    }
    size_t base = hoff + ((size_t)(g * NB + bb) * DI + d) * DST;
    #pragma unroll
    for (int s = 0; s < DST; s += 4) {
        *(float4*)(hend  + base + s) = make_float4(h[s], h[s+1], h[s+2], h[s+3]);
        *(float4*)(aprod + base + s) = make_float4(ap[s], ap[s+1], ap[s+2], ap[s+3]);
    }
}

__global__ __launch_bounds__(256) void scan2_k(
    float* __restrict__ hend, const float* __restrict__ aprod, int G)
{
    int dirv = blockIdx.y;
    int idx = blockIdx.x * 256 + threadIdx.x;
    const int slab = NB * DI * DST;
    size_t hoff = (size_t)dirv * G * slab;
    float carry = 0.f;
    for (int g = 0; g < G; ++g) {
        size_t off = hoff + (size_t)g * slab + idx;
        float a = aprod[off];
        float e = hend[off];
        hend[off] = carry;
        carry = fmaf(a, carry, e);
    }
}

__global__ __launch_bounds__(256) void scan3_k(
    const __hip_bfloat16* __restrict__ dtf2, const __hip_bfloat16* __restrict__ xsb2,
    const float* __restrict__ xdb2, const __hip_bfloat16* __restrict__ xz2,
    const float* __restrict__ fA, const float* __restrict__ bA,
    const float* __restrict__ fD, const float* __restrict__ bD,
    const float* __restrict__ hin, __hip_bfloat16* __restrict__ ycat, int G, int Cn)
{
    int d  = blockIdx.x * 256 + threadIdx.x;
    int bb = blockIdx.y;
    int zz = blockIdx.z;
    int dirv = (zz >= G) ? 1 : 0;
    int g = zz - (dirv ? G : 0);
    const float* A_log = dirv ? bA : fA;
    const float* Dskip = dirv ? bD : fD;
    const __hip_bfloat16* dtf = dtf2 + (size_t)dirv * MR * DI;
    const __hip_bfloat16* xs = xsb2 + (size_t)dirv * MR * DI;
    const float* xdb = xdb2 + (size_t)dirv * MR * XLD;
    const __hip_bfloat16* xz = xz2 + (size_t)dirv * MR * 2 * DI;
    size_t hoff = (size_t)dirv * G * (NB * DI * DST);

    float Ad[DST], h[DST];
    bool pw = true;
    size_t base = hoff + ((size_t)(g * NB + bb) * DI + d) * DST;
    #pragma unroll
    for (int s = 0; s < DST; ++s) {
        Ad[s] = -__expf(A_log[d * DST + s]);
        pw = pw && (fabsf(Ad[s] + (float)(s + 1)) < 1e-3f * (s + 1));
        h[s] = hin[base + s];
    }
    float Dsk = Dskip[d];
    int i0 = g * Cn;
    for (int i = 0; i < Cn; ++i) {
        int ii = i0 + i;
        int t = dirv ? (LL - 1 - ii) : ii;
        size_t m = (size_t)bb * LL + t;
        float dtv = bf2f(dtf[m * DI + d]);
        float xv  = bf2f(xs[m * DI + d]);
        const float* bc = xdb + m * XLD;
        float dtx = dtv * xv;
        float dAv[DST];
        if (pw) {
            float r = __expf(-dtv);
            float a = r;
            #pragma unroll
            for (int s = 0; s < DST; ++s) { dAv[s] = a; a *= r; }
        } else {
            #pragma unroll
            for (int s = 0; s < DST; ++s) dAv[s] = __expf(dtv * Ad[s]);
        }
        float yv = 0.f;
        #pragma unroll
        for (int s = 0; s < DST; ++s) {
            h[s] = fmaf(h[s], dAv[s], dtx * bc[64 + s]);
            yv = fmaf(h[s], bc[80 + s], yv);
        }
        float zv = bf2f(xz[m * (2 * DI) + DI + d]);
        ycat[m * (2 * DI) + (size_t)dirv * DI + d] =
            __float2bfloat16((yv + xv * Dsk) * siluf(zv));
    }
}

// fallback monolithic scan (both dirs) if ws too small for chunk bufs
__global__ __launch_bounds__(256) void scan_mono_k(
    const __hip_bfloat16* __restrict__ dtf2, const __hip_bfloat16* __restrict__ xsb2,
    const float* __restrict__ xdb2, const __hip_bfloat16* __restrict__ xz2,
    const float* __restrict__ fA, const float* __restrict__ bA,
    const float* __restrict__ fD, const float* __restrict__ bD,
    __hip_bfloat16* __restrict__ ycat)
{
    int d  = blockIdx.x * 256 + threadIdx.x;
    int bb = blockIdx.y;
    int dirv = blockIdx.z;
    const float* A_log = dirv ? bA : fA;
    const float* Dskip = dirv ? bD : fD;
    const __hip_bfloat16* dtf = dtf2 + (size_t)dirv * MR * DI;
    const __hip_bfloat16* xs = xsb2 + (size_t)dirv * MR * DI;
    const float* xdb = xdb2 + (size_t)dirv * MR * XLD;
    const __hip_bfloat16* xz = xz2 + (size_t)dirv * MR * 2 * DI;
    float Ad[DST], h[DST];
    #pragma unroll
    for (int s = 0; s < DST; ++s) { Ad[s] = -__expf(A_log[d * DST + s]); h[s] = 0.f; }
    float Dsk = Dskip[d];
    for (int i = 0; i < LL; ++i) {
        int t = dirv ? (LL - 1 - i) : i;
        size_t m = (size_t)bb * LL + t;
        float dtv = bf2f(dtf[m * DI + d]);
        float xv  = bf2f(xs[m * DI + d]);
        const float* bc = xdb + m * XLD;
        float dtx = dtv * xv;
        float yv = 0.f;
        #pragma unroll
        for (int s = 0; s < DST; ++s) {
            float dA = __expf(dtv * Ad[s]);
            h[s] = fmaf(h[s], dA, dtx * bc[64 + s]);
            yv = fmaf(h[s], bc[80 + s], yv);
        }
        float zv = bf2f(xz[m * (2 * DI) + DI + d]);
        ycat[m * (2 * DI) + (size_t)dirv * DI + d] =
            __float2bfloat16((yv + xv * Dsk) * siluf(zv));
    }
}

// ---------------- Launch ----------------
extern "C" void kernel_launch(void* const* d_in, const int* in_sizes, int n_in,
                              void* d_out, int out_size, void* d_ws, size_t ws_size,
                              hipStream_t stream)
{
    const float* x      = (const float*)d_in[0];
    const float* ln_w   = (const float*)d_in[1];
    const float* ln_b   = (const float*)d_in[2];
    const float* f_inW    = (const float*)d_in[3];
    const float* f_convW  = (const float*)d_in[4];
    const float* f_convb  = (const float*)d_in[5];
    const float* f_xprojW = (const float*)d_in[6];
    const float* f_dtW    = (const float*)d_in[7];
    const float* f_dtb    = (const float*)d_in[8];
    const float* f_A_log  = (const float*)d_in[9];
    const float* f_Dskip  = (const float*)d_in[10];
    const float* f_outW   = (const float*)d_in[11];
    const float* b_inW    = (const float*)d_in[12];
    const float* b_convW  = (const float*)d_in[13];
    const float* b_convb  = (const float*)d_in[14];
    const float* b_xprojW = (const float*)d_in[15];
    const float* b_dtW    = (const float*)d_in[16];
    const float* b_dtb    = (const float*)d_in[17];
    const float* b_A_log  = (const float*)d_in[18];
    const float* b_Dskip  = (const float*)d_in[19];
    const float* b_outW   = (const float*)d_in[20];
    const float* proj_W = (const float*)d_in[21];
    const float* proj_b = (const float*)d_in[22];

    float* ws = (float*)d_ws;
    size_t o = 0;
    __hip_bfloat16* xz2  = (__hip_bfloat16*)(ws + o);
    o += (size_t)2 * MR * 2 * DI / 2;
    __hip_bfloat16* xsb2 = (__hip_bfloat16*)(ws + o); o += (size_t)2 * MR * DI / 2;
    __hip_bfloat16* ycat = (__hip_bfloat16*)(ws + o);
    float* xpart = ws + o;
    o += (size_t)MR * 2 * DI / 2;
    float* xdb2 = ws + o; o += (size_t)2 * MR * XLD;
    __hip_bfloat16* xdbt = (__hip_bfloat16*)(ws + o); o += (size_t)2 * MR * 64 / 2;
    __hip_bfloat16* dtfb = (__hip_bfloat16*)(ws + o); o += (size_t)2 * MR * DI / 2;
    __hip_bfloat16* nb = (__hip_bfloat16*)(ws + o); o += (size_t)MR * DM / 2;
    __hip_bfloat16* warena = (__hip_bfloat16*)(ws + o); o += 15466496 / 2;
    float* hbuf = ws + o;
    size_t base_floats = o;

    __hip_bfloat16* wbi  = warena;               // [2][2DI][DM]    8,388,608
    __hip_bfloat16* pwb  = warena +  8388608;    // [DM][2DM]       2,097,152
    __hip_bfloat16* wdt  = warena + 10485760;    // [2][DI][64]       262,144
    __hip_bfloat16* wpb2 = warena + 10747904;    // [2][128][DI]      524,288
    __hip_bfloat16* wcat = warena + 11272192;    // [DM][2DI]       4,194,304

    const size_t slab = (size_t)NB * DI * DST;   // 65536
    int G = 32;
    while (G > 4 && (base_floats + 4ull * G * slab) * 4 > ws_size) G >>= 1;
    int useChunks = ((base_floats + 4ull * G * slab) * 4 <= ws_size);
    float* hend  = hbuf;
    float* aprod = hbuf + 2ull * G * slab;
    int Cn = useChunks ? LL / G : LL;

    // wot [2][DI][DM] bf16: in hbuf when chunked; else aliases xz2 (Wcat first).
    int wotInHbuf = useChunks && (4ull * G * slab >= 2097152ull);
    __hip_bfloat16* wot = wotInHbuf ? (__hip_bfloat16*)hbuf : xz2;

    // 1: mega-prep (weight cvts + transpose + layernorm)
    prep_k<<<5824, 256, 0, stream>>>(
        f_inW, b_inW, proj_W, f_dtW, b_dtW, warena,
        f_xprojW, b_xprojW, wpb2,
        f_outW, b_outW, wot,
        x, ln_w, ln_b, nb);

    // 2-3: in-proj (256x128, 2 blocks/CU), then merged conv+wcat
    if (wotInHbuf) {
        inproj256_k<<<512, 512, 0, stream>>>(nb, wbi, xz2);
        conv_wcat_k<<<1280, 256, 0, stream>>>(
            xz2, f_convW, f_convb, b_convW, b_convb, xsb2, pwb, wot, wcat);
    } else {
        gemm_gl<1><<<dim3(DI / 128, DM / 128, 2), 256, 0, stream>>>(
            pwb, 2 * DM, (size_t)DM, wot, DM, (size_t)DI * DM,
            wcat, 2 * DI, (size_t)DI, DM, nullptr, nullptr);
        inproj256_k<<<512, 512, 0, stream>>>(nb, wbi, xz2);
        conv_silu_k<<<dim3(MR / 4, 2), 256, 0, stream>>>(
            xz2, f_convW, f_convb, b_convW, b_convb, xsb2);
    }

    // 4-5: x-proj split-K + reduce
    xproj_part_k<<<dim3(KS, MR / 128, 2), 256, 0, stream>>>(xsb2, wpb2, xpart);
    xproj_reduce_k<<<dim3((MR * XLD) / 1024, 2), 256, 0, stream>>>(xpart, xdb2, xdbt);

    // 6: dt-proj both dirs: dtfb = softplus(xdbt @ dtW^T + dtb) (bf16)
    gemm_gl<3><<<dim3(DI / 128, MR / 128, 2), 256, 0, stream>>>(
        xdbt, 64, (size_t)MR * 64, wdt, 64, (size_t)DI * 64,
        dtfb, DI, (size_t)MR * DI, 64, f_dtb, b_dtb);

    // 7-9: selective scan both dirs -> ycat [MR][2*DI]  (3-dispatch, proven)
    if (useChunks) {
        scan1_k<<<dim3(DI / 256, NB, 2 * G), 256, 0, stream>>>(
            dtfb, xsb2, xdb2, f_A_log, b_A_log, hend, aprod, G, Cn);
        scan2_k<<<dim3((NB * DI * DST) / 256, 2), 256, 0, stream>>>(hend, aprod, G);
        scan3_k<<<dim3(DI / 256, NB, 2 * G), 256, 0, stream>>>(
            dtfb, xsb2, xdb2, xz2, f_A_log, b_A_log, f_Dskip, b_Dskip,
            hend, ycat, G, Cn);
    } else {
        scan_mono_k<<<dim3(DI / 256, NB, 2), 256, 0, stream>>>(
            dtfb, xsb2, xdb2, xz2, f_A_log, b_A_log, f_Dskip, b_Dskip, ycat);
    }

    // 10: fused out-proj: out = x + proj_b + ycat @ wcat^T
    outproj_k<<<dim3(DM / 64, MR / 64), 256, 0, stream>>>(
        ycat, wcat, x, proj_b, (float*)d_out);
}